// Round 11
// baseline (819.583 us; speedup 1.0000x reference)
//
#include <hip/hip_runtime.h>
#include <hip/hip_bf16.h>
#include <string.h>

#define N_NODES 50000
#define N_PAD 50048 /* 391*128 */
#define NBY 391
#define N_EDGES 400000
#define EP (N_EDGES + N_NODES) /* 450000 with self loops */
#define N_GRAPHS 256
#define EMB 64
#define HID 128
#define HEADS 4
#define GDIM 256
#define NUM_CLASSES 20
#define EPS_BN 1e-5f
#define NEG_SLOPE 0.2f
#define NB_AGG 2048

typedef __attribute__((ext_vector_type(8))) short short8;
typedef __attribute__((ext_vector_type(4))) float f32x4;
typedef __attribute__((ext_vector_type(2))) unsigned u32x2;
typedef __attribute__((ext_vector_type(4))) unsigned u32x4;

#define GLD(g, l)                                                              \
    __builtin_amdgcn_global_load_lds(                                          \
        (const __attribute__((address_space(1))) void*)(g),                    \
        (__attribute__((address_space(3))) void*)(l), 16, 0, 0)

__device__ __forceinline__ unsigned short f2b(float x) {
    union { float f; unsigned u; } a; a.f = x;
    unsigned r = a.u + 0x7FFF + ((a.u >> 16) & 1);
    return (unsigned short)(r >> 16);
}
__device__ __forceinline__ float b2f(unsigned short h) {
    union { unsigned u; float f; } a; a.u = (unsigned)h << 16;
    return a.f;
}
// non-temporal stores: stream outputs to HBM without LLC allocation
__device__ __forceinline__ void nts8(void* p, ushort4 v) {
    u32x2 u;
    memcpy(&u, &v, 8);
    __builtin_nontemporal_store(u, (u32x2*)p);
}
__device__ __forceinline__ void nts16(void* p, float4 v) {
    u32x4 u;
    memcpy(&u, &v, 16);
    __builtin_nontemporal_store(u, (u32x4*)p);
}
__device__ __forceinline__ void nts8f(void* p, float2 v) {
    u32x2 u;
    memcpy(&u, &v, 8);
    __builtin_nontemporal_store(u, (u32x2*)p);
}

// ---------------- node features ----------------
__global__ void k_node_init(const int* __restrict__ x, const float* __restrict__ depth,
                            const float* __restrict__ emb_table, const float* __restrict__ dw,
                            const float* __restrict__ db, float* __restrict__ h) {
    int i = blockIdx.x * blockDim.x + threadIdx.x;
    if (i >= N_NODES * EMB) return;
    int n = i >> 6, c = i & 63;
    h[i] = emb_table[x[n] * EMB + c] + depth[n] * dw[c] + db[c];
}

// ---------------- CSR build ----------------
__global__ void k_deg(const int* __restrict__ ei, int* __restrict__ deg) {
    int e = blockIdx.x * blockDim.x + threadIdx.x;
    if (e >= EP) return;
    int dst = (e < N_EDGES) ? ei[N_EDGES + e] : (e - N_EDGES);
    atomicAdd(&deg[dst], 1);
}

__global__ void k_scanA(const int* __restrict__ deg, int* __restrict__ incl, int* __restrict__ bsums) {
    __shared__ int sh[1024];
    int t = threadIdx.x;
    int i = blockIdx.x * 1024 + t;
    int v = (i < N_NODES) ? deg[i] : 0;
    int xv = v;
    sh[t] = xv;
    __syncthreads();
    for (int off = 1; off < 1024; off <<= 1) {
        int y = (t >= off) ? sh[t - off] : 0;
        __syncthreads();
        xv += y;
        sh[t] = xv;
        __syncthreads();
    }
    if (i < N_NODES) incl[i] = xv;
    if (t == 1023) bsums[blockIdx.x] = xv;
}

__global__ void k_scanB(int* __restrict__ bsums, int nb) {
    if (threadIdx.x == 0 && blockIdx.x == 0) {
        int run = 0;
        for (int b = 0; b < nb; b++) { int v = bsums[b]; bsums[b] = run; run += v; }
    }
}

__global__ void k_scanC(const int* __restrict__ incl, const int* __restrict__ deg,
                        const int* __restrict__ bsums, int* __restrict__ offs) {
    int i = blockIdx.x * blockDim.x + threadIdx.x;
    if (i < N_NODES) offs[i] = incl[i] - deg[i] + bsums[i >> 10];
    if (i == 0) offs[N_NODES] = EP;
}

__global__ void k_scatter(const int* __restrict__ ei, const int* __restrict__ offs,
                          int* __restrict__ cnt, int* __restrict__ csr) {
    int e = blockIdx.x * blockDim.x + threadIdx.x;
    if (e >= EP) return;
    int src, dst;
    if (e < N_EDGES) { src = ei[e]; dst = ei[N_EDGES + e]; }
    else { src = e - N_EDGES; dst = src; }
    int pos = atomicAdd(&cnt[dst], 1);
    csr[offs[dst] + pos] = src;
}

// ---------------- split fp32 -> bf16 hi/lo (weights; + zero BN accumulator) ----------------
__global__ __launch_bounds__(256) void k_split(const float* __restrict__ in,
                                               unsigned short* __restrict__ hi,
                                               unsigned short* __restrict__ lo,
                                               float* __restrict__ bnz,
                                               int total4, int real) {
    if (blockIdx.x == 0 && bnz) {
        for (int tt = threadIdx.x; tt < 1024; tt += 256) bnz[tt] = 0.f;
    }
    int i = blockIdx.x * blockDim.x + threadIdx.x;
    if (i >= total4) return;
    int f = i * 4;
    float4 v = make_float4(0.f, 0.f, 0.f, 0.f);
    if (f < real) v = *(const float4*)(in + f);
    ushort4 h, l;
    h.x = f2b(v.x); l.x = f2b(v.x - b2f(h.x));
    h.y = f2b(v.y); l.y = f2b(v.y - b2f(h.y));
    h.z = f2b(v.z); l.z = f2b(v.z - b2f(h.z));
    h.w = f2b(v.w); l.w = f2b(v.w - b2f(h.w));
    *(ushort4*)(hi + f) = h;
    *(ushort4*)(lo + f) = l;
}

// ---------------- in-place BN+ELU on hi/lo (scale computed inline from sums) ----------------
__global__ __launch_bounds__(256) void k_bnsplit(unsigned short* __restrict__ hi,
                                                 unsigned short* __restrict__ lo,
                                                 const float* __restrict__ sums,
                                                 const float* __restrict__ gamma,
                                                 const float* __restrict__ beta,
                                                 int M, int total4) {
    int i = blockIdx.x * blockDim.x + threadIdx.x;
    if (i >= total4) return;
    int f = i * 4;
    int c = f & (M - 1);
    float4 s4 = *(const float4*)(sums + c);
    float4 q4 = *(const float4*)(sums + M + c);
    float4 g4 = *(const float4*)(gamma + c);
    float4 be4 = *(const float4*)(beta + c);
    const float invN = 1.f / (float)N_NODES;
    float4 sc, sh;
    {
        float m = s4.x * invN; float var = q4.x * invN - m * m;
        sc.x = g4.x * __frsqrt_rn(var + EPS_BN); sh.x = be4.x - m * sc.x;
        m = s4.y * invN; var = q4.y * invN - m * m;
        sc.y = g4.y * __frsqrt_rn(var + EPS_BN); sh.y = be4.y - m * sc.y;
        m = s4.z * invN; var = q4.z * invN - m * m;
        sc.z = g4.z * __frsqrt_rn(var + EPS_BN); sh.z = be4.z - m * sc.z;
        m = s4.w * invN; var = q4.w * invN - m * m;
        sc.w = g4.w * __frsqrt_rn(var + EPS_BN); sh.w = be4.w - m * sc.w;
    }
    ushort4 h4 = *(const ushort4*)(hi + f);
    ushort4 l4 = *(const ushort4*)(lo + f);
    float4 v;
    v.x = b2f(h4.x) + b2f(l4.x);
    v.y = b2f(h4.y) + b2f(l4.y);
    v.z = b2f(h4.z) + b2f(l4.z);
    v.w = b2f(h4.w) + b2f(l4.w);
    float x;
    x = v.x * sc.x + sh.x; v.x = x > 0.f ? x : expm1f(x);
    x = v.y * sc.y + sh.y; v.y = x > 0.f ? x : expm1f(x);
    x = v.z * sc.z + sh.z; v.z = x > 0.f ? x : expm1f(x);
    x = v.w * sc.w + sh.w; v.w = x > 0.f ? x : expm1f(x);
    ushort4 h, l;
    h.x = f2b(v.x); l.x = f2b(v.x - b2f(h.x));
    h.y = f2b(v.y); l.y = f2b(v.y - b2f(h.y));
    h.z = f2b(v.z); l.z = f2b(v.z - b2f(h.z));
    h.w = f2b(v.w); l.w = f2b(v.w - b2f(h.w));
    *(ushort4*)(hi + f) = h;
    *(ushort4*)(lo + f) = l;
}

// ---------------- layer-0 h-space helpers ----------------
__global__ void k_wproj(const float* __restrict__ W0, const float* __restrict__ as_,
                        const float* __restrict__ ad_, float* __restrict__ wtil) {
    int t = threadIdx.x;  // 256
    int h = t >> 6, k = t & 63;
    float ss = 0.f, sd = 0.f;
    for (int c = 0; c < 128; c++) {
        float w = W0[(size_t)(h * 128 + c) * 64 + k];
        ss += w * as_[h * 128 + c];
        sd += w * ad_[h * 128 + c];
    }
    wtil[t] = ss;
    wtil[256 + t] = sd;
}

__global__ __launch_bounds__(256) void k_al0(const float* __restrict__ h0,
                                             const float* __restrict__ wtil,
                                             float* __restrict__ als, float* __restrict__ ald,
                                             float* __restrict__ bnz) {
    if (blockIdx.x == 0) {
        for (int t = threadIdx.x; t < 1024; t += 256) bnz[t] = 0.f;
    }
    int wid = threadIdx.x >> 6, lane = threadIdx.x & 63;
    int n = blockIdx.x * 4 + wid;
    if (n >= N_NODES) return;
    float v = h0[(size_t)n * 64 + lane];
#pragma unroll
    for (int h = 0; h < 4; h++) {
        float ps = v * wtil[h * 64 + lane];
        float pd = v * wtil[256 + h * 64 + lane];
        for (int off = 32; off; off >>= 1) {
            ps += __shfl_xor(ps, off);
            pd += __shfl_xor(pd, off);
        }
        if (lane == 0) { als[n * 4 + h] = ps; ald[n * 4 + h] = pd; }
    }
}

// layer-0 aggregate in h-space: QUARTER-WAVE per node (4 nodes/wave in lockstep).
__global__ __launch_bounds__(256) void k_agg0(const float* __restrict__ h0,
                                              const float* __restrict__ als,
                                              const float* __restrict__ ald_g,
                                              const int* __restrict__ offs,
                                              const int* __restrict__ csr,
                                              unsigned short* __restrict__ outh,
                                              unsigned short* __restrict__ outl) {
    const int lane = threadIdx.x & 63;
    const int wwid = threadIdx.x >> 6;
    const int q = lane >> 4, l = lane & 15;
    const int gw = blockIdx.x * 4 + wwid;
    const int stride = gridDim.x * 16;
    for (int n = gw * 4 + q; n < N_NODES; n += stride) {
        int s0 = offs[n], s1 = offs[n + 1];
        float aldl = (l < 4) ? ald_g[n * 4 + l] : 0.f;
        float acc[4][4] = {};
        float den[4] = {};
        int e = s0;
        for (; e + 2 <= s1; e += 2) {
            int srcA = csr[e], srcB = csr[e + 1];
            float wA = 0.f, wB = 0.f;
            if (l < 4) {
                float a1 = als[srcA * 4 + l] + aldl;
                a1 = a1 > 0.f ? a1 : NEG_SLOPE * a1;
                wA = expf(a1);
                float a2 = als[srcB * 4 + l] + aldl;
                a2 = a2 > 0.f ? a2 : NEG_SLOPE * a2;
                wB = expf(a2);
            }
            float4 vA = *(const float4*)(h0 + (size_t)srcA * 64 + l * 4);
            float4 vB = *(const float4*)(h0 + (size_t)srcB * 64 + l * 4);
#pragma unroll
            for (int h = 0; h < 4; h++) {
                float whA = __shfl(wA, q * 16 + h);
                float whB = __shfl(wB, q * 16 + h);
                den[h] += whA + whB;
                acc[h][0] += whA * vA.x + whB * vB.x;
                acc[h][1] += whA * vA.y + whB * vB.y;
                acc[h][2] += whA * vA.z + whB * vB.z;
                acc[h][3] += whA * vA.w + whB * vB.w;
            }
        }
        for (; e < s1; e++) {
            int src = csr[e];
            float w = 0.f;
            if (l < 4) {
                float a1 = als[src * 4 + l] + aldl;
                a1 = a1 > 0.f ? a1 : NEG_SLOPE * a1;
                w = expf(a1);
            }
            float4 v = *(const float4*)(h0 + (size_t)src * 64 + l * 4);
#pragma unroll
            for (int h = 0; h < 4; h++) {
                float wh = __shfl(w, q * 16 + h);
                den[h] += wh;
                acc[h][0] += wh * v.x;
                acc[h][1] += wh * v.y;
                acc[h][2] += wh * v.z;
                acc[h][3] += wh * v.w;
            }
        }
#pragma unroll
        for (int h = 0; h < 4; h++) {
            float id = 1.f / den[h];
            float o0 = acc[h][0] * id, o1 = acc[h][1] * id;
            float o2 = acc[h][2] * id, o3 = acc[h][3] * id;
            ushort4 hh, ll;
            hh.x = f2b(o0); ll.x = f2b(o0 - b2f(hh.x));
            hh.y = f2b(o1); ll.y = f2b(o1 - b2f(hh.y));
            hh.z = f2b(o2); ll.z = f2b(o2 - b2f(hh.z));
            hh.w = f2b(o3); ll.w = f2b(o3 - b2f(hh.w));
            size_t idx = (size_t)n * 256 + h * 64 + l * 4;
            nts8(outh + idx, hh);
            nts8(outl + idx, ll);
        }
    }
}

// layer-0 block-diag MFMA GEMM + fused BN-stats epilogue
__global__ __launch_bounds__(256) void k_gemm0h(const unsigned short* __restrict__ Ahh,
                                                const unsigned short* __restrict__ Ahl,
                                                const unsigned short* __restrict__ Wh,
                                                const unsigned short* __restrict__ Wl,
                                                const float* __restrict__ bias,
                                                unsigned short* __restrict__ outh,
                                                unsigned short* __restrict__ outl,
                                                float* __restrict__ bnacc) {
    __shared__ short8 sAh[512], sAl[512], sWh[512], sWl[512];
    const int nbx = gridDim.x;
    const int d = blockIdx.y * nbx + blockIdx.x;
    const int by = (d / (8 * nbx)) * 8 + (d & 7);
    const int bx = (d >> 3) % nbx;
    if (by >= NBY) return;
    const int hd = bx;
    const int t = threadIdx.x;
    const int lane = t & 63;
    const int wid = t >> 6;
    const int wm = wid >> 1, wn = wid & 1;
    const int r0 = by * 128;
    const int l15 = lane & 15, quad = lane >> 4;
    f32x4 acc[4][4] = {};
    for (int kb = 0; kb < 64; kb += 32) {
#pragma unroll
        for (int r = 0; r < 2; r++) {
            int c = r * 256 + t;
            int row = c >> 2, q = c & 3;
            size_t gA = ((size_t)(r0 + row) * 256 + hd * 64 + kb) * 2 + q * 16;
            size_t gW = ((size_t)(hd * 128 + row) * 64 + kb) * 2 + q * 16;
            GLD((const char*)Ahh + gA, (char*)sAh + c * 16);
            GLD((const char*)Ahl + gA, (char*)sAl + c * 16);
            GLD((const char*)Wh + gW, (char*)sWh + c * 16);
            GLD((const char*)Wl + gW, (char*)sWl + c * 16);
        }
        __syncthreads();
        short8 a_h[4], a_l[4], w_h[4], w_l[4];
#pragma unroll
        for (int i = 0; i < 4; i++) {
            int ra = (wm * 64 + i * 16 + l15) * 4 + quad;
            int rw = (wn * 64 + i * 16 + l15) * 4 + quad;
            a_h[i] = sAh[ra]; a_l[i] = sAl[ra];
            w_h[i] = sWh[rw]; w_l[i] = sWl[rw];
        }
#pragma unroll
        for (int i = 0; i < 4; i++)
#pragma unroll
            for (int j = 0; j < 4; j++) {
                acc[i][j] = __builtin_amdgcn_mfma_f32_16x16x32_bf16(a_h[i], w_h[j], acc[i][j], 0, 0, 0);
                acc[i][j] = __builtin_amdgcn_mfma_f32_16x16x32_bf16(a_h[i], w_l[j], acc[i][j], 0, 0, 0);
                acc[i][j] = __builtin_amdgcn_mfma_f32_16x16x32_bf16(a_l[i], w_h[j], acc[i][j], 0, 0, 0);
            }
        __syncthreads();
    }
    float colsum[4] = {}, colsq[4] = {};
#pragma unroll
    for (int i = 0; i < 4; i++) {
        int gr = r0 + wm * 64 + i * 16 + quad * 4;
#pragma unroll
        for (int j = 0; j < 4; j++) {
            int gc = hd * 128 + wn * 64 + j * 16 + l15;
            float bv = bias[gc];
#pragma unroll
            for (int rg = 0; rg < 4; rg++) {
                int rr = gr + rg;
                if (rr < N_NODES) {
                    float o = acc[i][j][rg] + bv;
                    unsigned short hh = f2b(o);
                    size_t idx = (size_t)rr * 512 + gc;
                    outh[idx] = hh;
                    outl[idx] = f2b(o - b2f(hh));
                    colsum[j] += o;
                    colsq[j] += o * o;
                }
            }
        }
    }
#pragma unroll
    for (int j = 0; j < 4; j++) {
        colsum[j] += __shfl_xor(colsum[j], 16);
        colsum[j] += __shfl_xor(colsum[j], 32);
        colsq[j] += __shfl_xor(colsq[j], 16);
        colsq[j] += __shfl_xor(colsq[j], 32);
    }
    float* sS = (float*)sAh;
    float* sQ = (float*)sAl;
    __syncthreads();
    if (quad == 0) {
#pragma unroll
        for (int j = 0; j < 4; j++) {
            int c = wn * 64 + j * 16 + l15;
            sS[c * 2 + wm] = colsum[j];
            sQ[c * 2 + wm] = colsq[j];
        }
    }
    __syncthreads();
    if (t < 128) {
        atomicAdd(bnacc + hd * 128 + t, sS[t * 2] + sS[t * 2 + 1]);
        atomicAdd(bnacc + 512 + hd * 128 + t, sQ[t * 2] + sQ[t * 2 + 1]);
    }
}

// ---------------- bf16 hi/lo MFMA GEMM + fused attention-logit epilogue ----------------
__global__ __launch_bounds__(256) void k_gemm_mfma(const unsigned short* __restrict__ Ah,
                                                   const unsigned short* __restrict__ Al,
                                                   const unsigned short* __restrict__ Wh,
                                                   const unsigned short* __restrict__ Wl,
                                                   const float* __restrict__ a_src,
                                                   const float* __restrict__ a_dst,
                                                   float* __restrict__ als_g,
                                                   float* __restrict__ ald_g,
                                                   float* __restrict__ out,
                                                   int K, int M, int heads) {
    __shared__ short8 sAh[512], sAl[512], sWh[512], sWl[512];
    const int nbx = gridDim.x;
    const int d = blockIdx.y * nbx + blockIdx.x;
    const int by = (d / (8 * nbx)) * 8 + (d & 7);
    const int bx = (d >> 3) % nbx;
    if (by >= NBY) return;
    const int t = threadIdx.x;
    const int lane = t & 63;
    const int wid = t >> 6;
    const int wm = wid >> 1, wn = wid & 1;
    const int r0 = by * 128, c0 = bx * 128;
    const int l15 = lane & 15, quad = lane >> 4;
    f32x4 acc[4][4] = {};
    for (int kb = 0; kb < K; kb += 32) {
#pragma unroll
        for (int r = 0; r < 2; r++) {
            int c = r * 256 + t;
            int row = c >> 2, q = c & 3;
            size_t gA = ((size_t)(r0 + row) * K + kb) * 2 + q * 16;
            size_t gW = ((size_t)(c0 + row) * K + kb) * 2 + q * 16;
            GLD((const char*)Ah + gA, (char*)sAh + c * 16);
            GLD((const char*)Al + gA, (char*)sAl + c * 16);
            GLD((const char*)Wh + gW, (char*)sWh + c * 16);
            GLD((const char*)Wl + gW, (char*)sWl + c * 16);
        }
        __syncthreads();
        short8 a_h[4], a_l[4], w_h[4], w_l[4];
#pragma unroll
        for (int i = 0; i < 4; i++) {
            int ra = (wm * 64 + i * 16 + l15) * 4 + quad;
            int rw = (wn * 64 + i * 16 + l15) * 4 + quad;
            a_h[i] = sAh[ra]; a_l[i] = sAl[ra];
            w_h[i] = sWh[rw]; w_l[i] = sWl[rw];
        }
#pragma unroll
        for (int i = 0; i < 4; i++)
#pragma unroll
            for (int j = 0; j < 4; j++) {
                acc[i][j] = __builtin_amdgcn_mfma_f32_16x16x32_bf16(a_h[i], w_h[j], acc[i][j], 0, 0, 0);
                acc[i][j] = __builtin_amdgcn_mfma_f32_16x16x32_bf16(a_h[i], w_l[j], acc[i][j], 0, 0, 0);
                acc[i][j] = __builtin_amdgcn_mfma_f32_16x16x32_bf16(a_l[i], w_h[j], acc[i][j], 0, 0, 0);
            }
        __syncthreads();
    }
#pragma unroll
    for (int i = 0; i < 4; i++) {
        int gr = r0 + wm * 64 + i * 16 + quad * 4;
#pragma unroll
        for (int j = 0; j < 4; j++) {
            int gc = c0 + wn * 64 + j * 16 + l15;
#pragma unroll
            for (int rg = 0; rg < 4; rg++) {
                int rr = gr + rg;
                if (rr < N_NODES) out[(size_t)rr * M + gc] = acc[i][j][rg];
            }
        }
    }
    const int hd = bx;
    float ps[4][4] = {}, pd[4][4] = {};
#pragma unroll
    for (int j = 0; j < 4; j++) {
        int ch = wn * 64 + j * 16 + l15;
        float av = a_src[hd * 128 + ch];
        float dv = a_dst[hd * 128 + ch];
#pragma unroll
        for (int i = 0; i < 4; i++)
#pragma unroll
            for (int rg = 0; rg < 4; rg++) {
                ps[i][rg] += acc[i][j][rg] * av;
                pd[i][rg] += acc[i][j][rg] * dv;
            }
    }
#pragma unroll
    for (int m = 1; m < 16; m <<= 1)
#pragma unroll
        for (int i = 0; i < 4; i++)
#pragma unroll
            for (int rg = 0; rg < 4; rg++) {
                ps[i][rg] += __shfl_xor(ps[i][rg], m);
                pd[i][rg] += __shfl_xor(pd[i][rg], m);
            }
    float* sS = (float*)sAh;
    float* sD = (float*)sAl;
    if (l15 == 0) {
#pragma unroll
        for (int i = 0; i < 4; i++)
#pragma unroll
            for (int rg = 0; rg < 4; rg++) {
                int ri = wm * 64 + i * 16 + quad * 4 + rg;
                sS[ri * 2 + wn] = ps[i][rg];
                sD[ri * 2 + wn] = pd[i][rg];
            }
    }
    __syncthreads();
    if (t < 128) {
        int row = r0 + t;
        if (row < N_NODES) {
            als_g[row * heads + hd] = sS[t * 2] + sS[t * 2 + 1];
            ald_g[row * heads + hd] = sD[t * 2] + sD[t * 2 + 1];
        }
    }
}

// ---------------- fp32 GEMM fallback ----------------
#define BM 128
#define BN 128
#define BK 16
__global__ __launch_bounds__(256) void k_gemm(const float* __restrict__ Ain,
                                              const float* __restrict__ W,
                                              float* __restrict__ out,
                                              int Nrows, int K, int M) {
    __shared__ float As[BK][BM + 4];
    __shared__ float Ws[BK][BN + 4];
    int r0 = blockIdx.y * BM, c0 = blockIdx.x * BN;
    int t = threadIdx.x;
    int tx = t & 15, ty = t >> 4;
    float acc[8][8] = {};
    for (int kb = 0; kb < K; kb += BK) {
#pragma unroll
        for (int i = 0; i < 2; i++) {
            int lin = t + i * 256;
            int row = lin >> 2;
            int kq = (lin & 3) * 4;
            int gr = r0 + row;
            float4 v = make_float4(0.f, 0.f, 0.f, 0.f);
            if (gr < Nrows) v = *(const float4*)(Ain + (size_t)gr * K + kb + kq);
            As[kq + 0][row] = v.x; As[kq + 1][row] = v.y; As[kq + 2][row] = v.z; As[kq + 3][row] = v.w;
        }
#pragma unroll
        for (int i = 0; i < 2; i++) {
            int lin = t + i * 256;
            int row = lin >> 2;
            int kq = (lin & 3) * 4;
            int gm = c0 + row;
            float4 v = *(const float4*)(W + (size_t)gm * K + kb + kq);
            Ws[kq + 0][row] = v.x; Ws[kq + 1][row] = v.y; Ws[kq + 2][row] = v.z; Ws[kq + 3][row] = v.w;
        }
        __syncthreads();
#pragma unroll
        for (int k = 0; k < BK; k++) {
            float a[8], b[8];
#pragma unroll
            for (int i = 0; i < 4; i++) {
                float2 v = *(const float2*)&As[k][ty * 2 + 32 * i];
                a[2 * i] = v.x; a[2 * i + 1] = v.y;
            }
#pragma unroll
            for (int j = 0; j < 4; j++) {
                float2 v = *(const float2*)&Ws[k][tx * 2 + 32 * j];
                b[2 * j] = v.x; b[2 * j + 1] = v.y;
            }
#pragma unroll
            for (int i = 0; i < 8; i++)
#pragma unroll
                for (int j = 0; j < 8; j++) acc[i][j] += a[i] * b[j];
        }
        __syncthreads();
    }
#pragma unroll
    for (int i = 0; i < 8; i++) {
        int row = r0 + 32 * (i >> 1) + ty * 2 + (i & 1);
        if (row >= Nrows) continue;
#pragma unroll
        for (int j = 0; j < 4; j++) {
            int col = c0 + 32 * j + tx * 2;
            *(float2*)(out + (size_t)row * M + col) = make_float2(acc[i][2 * j], acc[i][2 * j + 1]);
        }
    }
}

// ---------------- attention logits (fallback path only; + zero BN acc) ----------------
__global__ __launch_bounds__(256) void k_al(const float* __restrict__ xf,
                                            const float* __restrict__ a_src,
                                            const float* __restrict__ a_dst,
                                            float* __restrict__ als, float* __restrict__ ald,
                                            float* __restrict__ bn_zero,
                                            int M, int heads) {
    if (blockIdx.x == 0) {
        for (int t = threadIdx.x; t < 1024; t += 256) bn_zero[t] = 0.f;
    }
    int wid = threadIdx.x >> 6, lane = threadIdx.x & 63;
    int n = blockIdx.x * 4 + wid;
    if (n >= N_NODES) return;
    for (int h = 0; h < heads; h++) {
        float x0 = xf[(size_t)n * M + h * 128 + lane];
        float x1 = xf[(size_t)n * M + h * 128 + 64 + lane];
        float ps = x0 * a_src[h * 128 + lane] + x1 * a_src[h * 128 + 64 + lane];
        float pd = x0 * a_dst[h * 128 + lane] + x1 * a_dst[h * 128 + 64 + lane];
        for (int off = 32; off; off >>= 1) {
            ps += __shfl_xor(ps, off);
            pd += __shfl_xor(pd, off);
        }
        if (lane == 0) { als[n * heads + h] = ps; ald[n * heads + h] = pd; }
    }
}

// ---------------- segment softmax aggregation (shift-free) + fused BN stats ----------------
// Round-8 structure + non-temporal output stores (keep LLC for the xf gather set).
template <int M, int NH, bool HL>
__global__ __launch_bounds__(256) void k_aggregate(const float* __restrict__ xf,
                                                   const float* __restrict__ als,
                                                   const float* __restrict__ ald_g,
                                                   const int* __restrict__ offs,
                                                   const int* __restrict__ csr,
                                                   const float* __restrict__ bias,
                                                   float* __restrict__ out_f,
                                                   unsigned short* __restrict__ out_h,
                                                   unsigned short* __restrict__ out_l,
                                                   float* __restrict__ bnacc) {
    __shared__ float pool[4][2 * M];
    const int wid = threadIdx.x >> 6, lane = threadIdx.x & 63;
    int* s_src = (int*)&pool[wid][0];
    float* s_w = &pool[wid][64];
    const int gw = blockIdx.x * 4 + wid;
    const int nw = gridDim.x * 4;
    if constexpr (M == 512) {
        const int c0 = lane * 4, c1 = 256 + lane * 4;
        const int h0 = lane >> 5;
        const int h1 = 2 + (lane >> 5);
        const float4 bias0 = *(const float4*)(bias + c0);
        const float4 bias1 = *(const float4*)(bias + c1);
        float bns[8] = {}, bnq[8] = {};
        for (int n = gw; n < N_NODES; n += nw) {
            int s0 = offs[n], s1 = offs[n + 1];
            float4 aldv = *(const float4*)(ald_g + n * 4);
            float4 a0 = make_float4(0.f, 0.f, 0.f, 0.f);
            float4 a1 = make_float4(0.f, 0.f, 0.f, 0.f);
            float den0 = 0.f, den1 = 0.f;
            for (int base = s0; base < s1; base += 64) {
                int j = base + lane;
                int srcj = 0;
                float4 alv = make_float4(0.f, 0.f, 0.f, 0.f);
                if (j < s1) {
                    srcj = csr[j];
                    alv = *(const float4*)(als + srcj * 4);
                }
                float e0 = alv.x + aldv.x; e0 = e0 > 0.f ? e0 : NEG_SLOPE * e0;
                float e1 = alv.y + aldv.y; e1 = e1 > 0.f ? e1 : NEG_SLOPE * e1;
                float e2 = alv.z + aldv.z; e2 = e2 > 0.f ? e2 : NEG_SLOPE * e2;
                float e3 = alv.w + aldv.w; e3 = e3 > 0.f ? e3 : NEG_SLOPE * e3;
                s_src[lane] = srcj;
                s_w[0 * 64 + lane] = expf(e0);
                s_w[1 * 64 + lane] = expf(e1);
                s_w[2 * 64 + lane] = expf(e2);
                s_w[3 * 64 + lane] = expf(e3);
                int cend = min(64, s1 - base);
                int e = 0;
                for (; e + 4 <= cend; e += 4) {
                    int sA = s_src[e], sB = s_src[e + 1];
                    int sC = s_src[e + 2], sD = s_src[e + 3];
                    float wAl = s_w[h0 * 64 + e],     wAh = s_w[h1 * 64 + e];
                    float wBl = s_w[h0 * 64 + e + 1], wBh = s_w[h1 * 64 + e + 1];
                    float wCl = s_w[h0 * 64 + e + 2], wCh = s_w[h1 * 64 + e + 2];
                    float wDl = s_w[h0 * 64 + e + 3], wDh = s_w[h1 * 64 + e + 3];
                    const float* rA = xf + (size_t)sA * 512;
                    const float* rB = xf + (size_t)sB * 512;
                    const float* rC = xf + (size_t)sC * 512;
                    const float* rD = xf + (size_t)sD * 512;
                    float4 vA0 = *(const float4*)(rA + c0);
                    float4 vA1 = *(const float4*)(rA + c1);
                    float4 vB0 = *(const float4*)(rB + c0);
                    float4 vB1 = *(const float4*)(rB + c1);
                    float4 vC0 = *(const float4*)(rC + c0);
                    float4 vC1 = *(const float4*)(rC + c1);
                    float4 vD0 = *(const float4*)(rD + c0);
                    float4 vD1 = *(const float4*)(rD + c1);
                    den0 += wAl + wBl + wCl + wDl;
                    den1 += wAh + wBh + wCh + wDh;
                    a0.x += wAl * vA0.x + wBl * vB0.x + wCl * vC0.x + wDl * vD0.x;
                    a0.y += wAl * vA0.y + wBl * vB0.y + wCl * vC0.y + wDl * vD0.y;
                    a0.z += wAl * vA0.z + wBl * vB0.z + wCl * vC0.z + wDl * vD0.z;
                    a0.w += wAl * vA0.w + wBl * vB0.w + wCl * vC0.w + wDl * vD0.w;
                    a1.x += wAh * vA1.x + wBh * vB1.x + wCh * vC1.x + wDh * vD1.x;
                    a1.y += wAh * vA1.y + wBh * vB1.y + wCh * vC1.y + wDh * vD1.y;
                    a1.z += wAh * vA1.z + wBh * vB1.z + wCh * vC1.z + wDh * vD1.z;
                    a1.w += wAh * vA1.w + wBh * vB1.w + wCh * vC1.w + wDh * vD1.w;
                }
                for (; e < cend; e++) {
                    int src = s_src[e];
                    float wA = s_w[h0 * 64 + e];
                    float wB = s_w[h1 * 64 + e];
                    const float* row = xf + (size_t)src * 512;
                    float4 v0 = *(const float4*)(row + c0);
                    float4 v1 = *(const float4*)(row + c1);
                    den0 += wA; den1 += wB;
                    a0.x += wA * v0.x; a0.y += wA * v0.y; a0.z += wA * v0.z; a0.w += wA * v0.w;
                    a1.x += wB * v1.x; a1.y += wB * v1.y; a1.z += wB * v1.z; a1.w += wB * v1.w;
                }
            }
            float id0 = 1.f / den0, id1 = 1.f / den1;
            float4 o0, o1;
            o0.x = a0.x * id0 + bias0.x; o0.y = a0.y * id0 + bias0.y;
            o0.z = a0.z * id0 + bias0.z; o0.w = a0.w * id0 + bias0.w;
            o1.x = a1.x * id1 + bias1.x; o1.y = a1.y * id1 + bias1.y;
            o1.z = a1.z * id1 + bias1.z; o1.w = a1.w * id1 + bias1.w;
            size_t f0 = (size_t)n * 512 + c0, f1 = (size_t)n * 512 + c1;
            if constexpr (HL) {
                ushort4 h4, l4;
                h4.x = f2b(o0.x); l4.x = f2b(o0.x - b2f(h4.x));
                h4.y = f2b(o0.y); l4.y = f2b(o0.y - b2f(h4.y));
                h4.z = f2b(o0.z); l4.z = f2b(o0.z - b2f(h4.z));
                h4.w = f2b(o0.w); l4.w = f2b(o0.w - b2f(h4.w));
                nts8(out_h + f0, h4);
                nts8(out_l + f0, l4);
                h4.x = f2b(o1.x); l4.x = f2b(o1.x - b2f(h4.x));
                h4.y = f2b(o1.y); l4.y = f2b(o1.y - b2f(h4.y));
                h4.z = f2b(o1.z); l4.z = f2b(o1.z - b2f(h4.z));
                h4.w = f2b(o1.w); l4.w = f2b(o1.w - b2f(h4.w));
                nts8(out_h + f1, h4);
                nts8(out_l + f1, l4);
            } else {
                nts16(out_f + f0, o0);
                nts16(out_f + f1, o1);
            }
            bns[0] += o0.x; bnq[0] += o0.x * o0.x;
            bns[1] += o0.y; bnq[1] += o0.y * o0.y;
            bns[2] += o0.z; bnq[2] += o0.z * o0.z;
            bns[3] += o0.w; bnq[3] += o0.w * o0.w;
            bns[4] += o1.x; bnq[4] += o1.x * o1.x;
            bns[5] += o1.y; bnq[5] += o1.y * o1.y;
            bns[6] += o1.z; bnq[6] += o1.z * o1.z;
            bns[7] += o1.w; bnq[7] += o1.w * o1.w;
        }
#pragma unroll
        for (int k = 0; k < 4; k++) {
            pool[wid][c0 + k] = bns[k];
            pool[wid][c1 + k] = bns[4 + k];
            pool[wid][512 + c0 + k] = bnq[k];
            pool[wid][512 + c1 + k] = bnq[4 + k];
        }
        __syncthreads();
        for (int t = threadIdx.x; t < 1024; t += 256)
            atomicAdd(bnacc + t, pool[0][t] + pool[1][t] + pool[2][t] + pool[3][t]);
    } else {  // M == 128, NH == 1
        const int c = lane * 2;
        const float2 biasv = *(const float2*)(bias + c);
        float bns0 = 0.f, bns1 = 0.f, bnq0 = 0.f, bnq1 = 0.f;
        for (int n = gw; n < N_NODES; n += nw) {
            int s0 = offs[n], s1 = offs[n + 1];
            float aldv = ald_g[n];
            float2 a = make_float2(0.f, 0.f);
            float den = 0.f;
            for (int base = s0; base < s1; base += 64) {
                int j = base + lane;
                int srcj = 0;
                float alv = 0.f;
                if (j < s1) { srcj = csr[j]; alv = als[srcj]; }
                float e0 = alv + aldv;
                e0 = e0 > 0.f ? e0 : NEG_SLOPE * e0;
                s_src[lane] = srcj;
                s_w[lane] = expf(e0);
                int cend = min(64, s1 - base);
                int e = 0;
                for (; e + 4 <= cend; e += 4) {
                    int sA = s_src[e], sB = s_src[e + 1];
                    int sC = s_src[e + 2], sD = s_src[e + 3];
                    float wA = s_w[e],     wB = s_w[e + 1];
                    float wC = s_w[e + 2], wD = s_w[e + 3];
                    float2 vA = *(const float2*)(xf + (size_t)sA * 128 + c);
                    float2 vB = *(const float2*)(xf + (size_t)sB * 128 + c);
                    float2 vC = *(const float2*)(xf + (size_t)sC * 128 + c);
                    float2 vD = *(const float2*)(xf + (size_t)sD * 128 + c);
                    den += wA + wB + wC + wD;
                    a.x += wA * vA.x + wB * vB.x + wC * vC.x + wD * vD.x;
                    a.y += wA * vA.y + wB * vB.y + wC * vC.y + wD * vD.y;
                }
                for (; e < cend; e++) {
                    int src = s_src[e];
                    float w = s_w[e];
                    float2 v = *(const float2*)(xf + (size_t)src * 128 + c);
                    den += w;
                    a.x += w * v.x; a.y += w * v.y;
                }
            }
            float id = 1.f / den;
            float2 o;
            o.x = a.x * id + biasv.x;
            o.y = a.y * id + biasv.y;
            nts8f(out_f + (size_t)n * 128 + c, o);
            bns0 += o.x; bnq0 += o.x * o.x;
            bns1 += o.y; bnq1 += o.y * o.y;
        }
        pool[wid][c] = bns0; pool[wid][c + 1] = bns1;
        pool[wid][128 + c] = bnq0; pool[wid][128 + c + 1] = bnq1;
        __syncthreads();
        for (int t = threadIdx.x; t < 256; t += 256)
            atomicAdd(bnacc + t, pool[0][t] + pool[1][t] + pool[2][t] + pool[3][t]);
    }
}

// ---------------- BN+ELU apply, fp32 (scale computed inline from sums) ----------------
__global__ __launch_bounds__(256) void k_bn_apply(float* __restrict__ h,
                                                  const float* __restrict__ sums,
                                                  const float* __restrict__ gamma,
                                                  const float* __restrict__ beta,
                                                  int M, int total4) {
    int i = blockIdx.x * blockDim.x + threadIdx.x;
    if (i >= total4) return;
    int f = i * 4;
    int c = f & (M - 1);
    float4 s4 = *(const float4*)(sums + c);
    float4 q4 = *(const float4*)(sums + M + c);
    float4 g4 = *(const float4*)(gamma + c);
    float4 be4 = *(const float4*)(beta + c);
    const float invN = 1.f / (float)N_NODES;
    float4 sc, sh;
    {
        float m = s4.x * invN; float var = q4.x * invN - m * m;
        sc.x = g4.x * __frsqrt_rn(var + EPS_BN); sh.x = be4.x - m * sc.x;
        m = s4.y * invN; var = q4.y * invN - m * m;
        sc.y = g4.y * __frsqrt_rn(var + EPS_BN); sh.y = be4.y - m * sc.y;
        m = s4.z * invN; var = q4.z * invN - m * m;
        sc.z = g4.z * __frsqrt_rn(var + EPS_BN); sh.z = be4.z - m * sc.z;
        m = s4.w * invN; var = q4.w * invN - m * m;
        sc.w = g4.w * __frsqrt_rn(var + EPS_BN); sh.w = be4.w - m * sc.w;
    }
    float4 v = *(float4*)(h + f);
    float x;
    x = v.x * sc.x + sh.x; v.x = x > 0.f ? x : expm1f(x);
    x = v.y * sc.y + sh.y; v.y = x > 0.f ? x : expm1f(x);
    x = v.z * sc.z + sh.z; v.z = x > 0.f ? x : expm1f(x);
    x = v.w * sc.w + sh.w; v.w = x > 0.f ? x : expm1f(x);
    *(float4*)(h + f) = v;
}

// ---------------- pooling + classifier ----------------
__global__ void k_graph_bounds(const int* __restrict__ batch, int* __restrict__ goffs) {
    int n = blockIdx.x * blockDim.x + threadIdx.x;
    if (n >= N_NODES) return;
    int b = batch[n];
    int bp = (n == 0) ? -1 : batch[n - 1];
    for (int g = bp + 1; g <= b; g++) goffs[g] = n;
    if (n == N_NODES - 1) {
        for (int g = b + 1; g <= N_GRAPHS; g++) goffs[g] = N_NODES;
    }
}

__global__ void k_pool(const float* __restrict__ h, const int* __restrict__ goffs, float* __restrict__ emb) {
    int g = blockIdx.x;
    int c = threadIdx.x;
    int s = goffs[g], e = goffs[g + 1];
    float sum = 0.f, mx = -INFINITY;
    for (int n = s; n < e; n++) {
        float v = h[(size_t)n * 128 + c];
        sum += v;
        mx = fmaxf(mx, v);
    }
    int cnt = e - s;
    emb[g * 256 + c] = sum / (float)max(cnt, 1);
    emb[g * 256 + 128 + c] = mx;
}

__global__ __launch_bounds__(256) void k_classify(const float* __restrict__ emb,
                                                  const float* __restrict__ cw1, const float* __restrict__ cb1,
                                                  const float* __restrict__ cw2, const float* __restrict__ cb2,
                                                  float* __restrict__ out) {
    __shared__ float er[256];
    __shared__ float hid[256];
    int g = blockIdx.x, t = threadIdx.x;
    er[t] = emb[g * 256 + t];
    __syncthreads();
    float acc = cb1[t];
    for (int k = 0; k < 256; k++) acc += er[k] * cw1[t * 256 + k];
    hid[t] = fmaxf(acc, 0.f);
    __syncthreads();
    if (t < NUM_CLASSES) {
        float o = cb2[t];
        for (int k = 0; k < 256; k++) o += hid[k] * cw2[t * 256 + k];
        out[g * NUM_CLASSES + t] = o;
    }
}

// ---------------- driver ----------------
extern "C" void kernel_launch(void* const* d_in, const int* in_sizes, int n_in,
                              void* d_out, int out_size, void* d_ws, size_t ws_size,
                              hipStream_t stream) {
    const int* x = (const int*)d_in[0];
    const int* ei = (const int*)d_in[1];
    const float* depth = (const float*)d_in[2];
    const int* batch = (const int*)d_in[3];
    const float* emb_table = (const float*)d_in[4];
    const float* depth_w = (const float*)d_in[5];
    const float* depth_b = (const float*)d_in[6];
    const float* W0 = (const float*)d_in[7];
    const float* as0 = (const float*)d_in[8];
    const float* ad0 = (const float*)d_in[9];
    const float* b0 = (const float*)d_in[10];
    const float* g0 = (const float*)d_in[11];
    const float* be0 = (const float*)d_in[12];
    const float* W1 = (const float*)d_in[13];
    const float* as1 = (const float*)d_in[14];
    const float* ad1 = (const float*)d_in[15];
    const float* b1 = (const float*)d_in[16];
    const float* g1 = (const float*)d_in[17];
    const float* be1 = (const float*)d_in[18];
    const float* W2 = (const float*)d_in[19];
    const float* as2 = (const float*)d_in[20];
    const float* ad2 = (const float*)d_in[21];
    const float* b2 = (const float*)d_in[22];
    const float* g2 = (const float*)d_in[23];
    const float* be2 = (const float*)d_in[24];
    const float* cw1 = (const float*)d_in[25];
    const float* cb1 = (const float*)d_in[26];
    const float* cw2 = (const float*)d_in[27];
    const float* cb2 = (const float*)d_in[28];
    float* out = (float*)d_out;

    // workspace carve — must stay <= 211,469,440 B (proven ws_size lower bound)
    size_t off = 0;
    char* base = (char*)d_ws;
    auto carve = [&](size_t bytes) -> void* {
        void* p = base + off;
        off += (bytes + 255) & ~(size_t)255;
        return p;
    };
    float* B = (float*)carve((size_t)N_NODES * 512 * 4);                     // 102.4 MB
    unsigned short* Ah = (unsigned short*)carve((size_t)N_NODES * 512 * 2);  // 51.2 MB
    unsigned short* Al = (unsigned short*)carve((size_t)N_NODES * 512 * 2);  // 51.2 MB
    unsigned short* Wh = (unsigned short*)carve((size_t)512 * 512 * 2);
    unsigned short* Wl = (unsigned short*)carve((size_t)512 * 512 * 2);
    float* als = (float*)carve((size_t)N_NODES * HEADS * 4);
    float* ald = (float*)carve((size_t)N_NODES * HEADS * 4);
    float* bn = (float*)carve(4 * 512 * 4);
    float* wtil = (float*)carve(512 * 4);
    float* emb = (float*)carve((size_t)N_GRAPHS * 256 * 4);
    int* deg = (int*)carve((size_t)N_NODES * 4);
    int* cnt = (int*)carve((size_t)N_NODES * 4);
    int* incl = (int*)carve((size_t)N_NODES * 4);
    int* offs = (int*)carve((size_t)(N_NODES + 1) * 4);
    int* bsums = (int*)carve(64 * 4);
    int* csr = (int*)carve((size_t)EP * 4);
    int* goffs = (int*)carve((size_t)(N_GRAPHS + 1) * 4);
    const bool mfma_ok = (off <= ws_size);
    float* Afp = (float*)Ah;  // fallback fp32 buffer aliases Ah+Al
    float* C = (float*)Ah;    // layer-2 fp32 scratch reuses Ah region
    // layer-0 h-space buffers inside B region:
    float* h0 = B;
    unsigned short* hth = (unsigned short*)((char*)B + (size_t)N_NODES * 64 * 4);
    unsigned short* htl = (unsigned short*)((char*)hth + (size_t)N_PAD * 256 * 2);

    const int TPB = 256;
    int gbN = (N_NODES + TPB - 1) / TPB;
    int gbE = (EP + TPB - 1) / TPB;
    int nbScan = (N_NODES + 1023) / 1024;

    hipMemsetAsync(deg, 0, (size_t)N_NODES * 4, stream);
    hipMemsetAsync(cnt, 0, (size_t)N_NODES * 4, stream);
    k_deg<<<gbE, TPB, 0, stream>>>(ei, deg);
    k_scanA<<<nbScan, 1024, 0, stream>>>(deg, incl, bsums);
    k_scanB<<<1, 64, 0, stream>>>(bsums, nbScan);
    k_scanC<<<gbN, TPB, 0, stream>>>(incl, deg, bsums, offs);
    k_scatter<<<gbE, TPB, 0, stream>>>(ei, offs, cnt, csr);
    k_graph_bounds<<<gbN, TPB, 0, stream>>>(batch, goffs);

    int gbNode4 = (N_NODES + 3) / 4;
    dim3 g512(4, 392);  // swizzled: 392 = ceil(391/8)*8
    dim3 g128(1, 391);

    if (mfma_ok) {
        // ---- layer 0 (h-space aggregation; x0 = (sum_e a_e h[src]) @ W0^T + b0) ----
        k_node_init<<<(N_NODES * EMB + TPB - 1) / TPB, TPB, 0, stream>>>(x, depth, emb_table, depth_w, depth_b, h0);
        k_wproj<<<1, TPB, 0, stream>>>(W0, as0, ad0, wtil);
        k_split<<<(512 * 64 / 4 + TPB - 1) / TPB, TPB, 0, stream>>>(W0, Wh, Wl, nullptr, 512 * 64 / 4, 512 * 64);
        k_al0<<<gbNode4, TPB, 0, stream>>>(h0, wtil, als, ald, bn);
        k_agg0<<<NB_AGG, TPB, 0, stream>>>(h0, als, ald, offs, csr, hth, htl);
        k_gemm0h<<<g512, TPB, 0, stream>>>(hth, htl, Wh, Wl, b0, Ah, Al, bn);
        k_bnsplit<<<(N_NODES * 512 / 4 + TPB - 1) / TPB, TPB, 0, stream>>>(Ah, Al, bn, g0, be0, 512, N_NODES * 512 / 4);
        // ---- layer 1: [N,512] -> [N,512] ----
        k_split<<<(512 * 512 / 4 + TPB - 1) / TPB, TPB, 0, stream>>>(W1, Wh, Wl, bn, 512 * 512 / 4, 512 * 512);
        k_gemm_mfma<<<g512, TPB, 0, stream>>>(Ah, Al, Wh, Wl, as1, ad1, als, ald, B, 512, 512, HEADS);
        k_aggregate<512, HEADS, true><<<NB_AGG, TPB, 0, stream>>>(B, als, ald, offs, csr, b1, nullptr, Ah, Al, bn);
        k_bnsplit<<<(N_NODES * 512 / 4 + TPB - 1) / TPB, TPB, 0, stream>>>(Ah, Al, bn, g1, be1, 512, N_NODES * 512 / 4);
        // ---- layer 2: [N,512] -> [N,128] ----
        k_split<<<(128 * 512 / 4 + TPB - 1) / TPB, TPB, 0, stream>>>(W2, Wh, Wl, bn, 128 * 512 / 4, 128 * 512);
        k_gemm_mfma<<<g128, TPB, 0, stream>>>(Ah, Al, Wh, Wl, as2, ad2, als, ald, B, 512, 128, 1);
    } else {
        k_node_init<<<(N_NODES * EMB + TPB - 1) / TPB, TPB, 0, stream>>>(x, depth, emb_table, depth_w, depth_b, Afp);
        int gbRows = N_PAD / 128;
        k_gemm<<<dim3(4, gbRows), TPB, 0, stream>>>(Afp, W0, B, N_NODES, 64, 512);
        k_al<<<gbNode4, TPB, 0, stream>>>(B, as0, ad0, als, ald, bn, 512, HEADS);
        k_aggregate<512, HEADS, false><<<NB_AGG, TPB, 0, stream>>>(B, als, ald, offs, csr, b0, Afp, nullptr, nullptr, bn);
        k_bn_apply<<<(N_NODES * 512 / 4 + TPB - 1) / TPB, TPB, 0, stream>>>(Afp, bn, g0, be0, 512, N_NODES * 512 / 4);
        k_gemm<<<dim3(4, gbRows), TPB, 0, stream>>>(Afp, W1, B, N_NODES, 512, 512);
        k_al<<<gbNode4, TPB, 0, stream>>>(B, as1, ad1, als, ald, bn, 512, HEADS);
        k_aggregate<512, HEADS, false><<<NB_AGG, TPB, 0, stream>>>(B, als, ald, offs, csr, b1, Afp, nullptr, nullptr, bn);
        k_bn_apply<<<(N_NODES * 512 / 4 + TPB - 1) / TPB, TPB, 0, stream>>>(Afp, bn, g1, be1, 512, N_NODES * 512 / 4);
        k_gemm<<<dim3(1, gbRows), TPB, 0, stream>>>(Afp, W2, B, N_NODES, 512, 128);
        k_al<<<gbNode4, TPB, 0, stream>>>(B, as2, ad2, als, ald, bn, 128, 1);
    }

    // ---- layer 2 tail (shared; bn zeroed by k_split W2 on mfma path, k_al on fallback) ----
    k_aggregate<128, 1, false><<<NB_AGG, TPB, 0, stream>>>(B, als, ald, offs, csr, b2, C, nullptr, nullptr, bn);
    k_bn_apply<<<(N_NODES * 128 / 4 + TPB - 1) / TPB, TPB, 0, stream>>>(C, bn, g2, be2, 128, N_NODES * 128 / 4);

    k_pool<<<N_GRAPHS, 128, 0, stream>>>(C, goffs, emb);
    k_classify<<<N_GRAPHS, TPB, 0, stream>>>(emb, cw1, cb1, cw2, cb2, out);
}

// Round 12
// 804.083 us; speedup vs baseline: 1.0193x; 1.0193x over previous
//
#include <hip/hip_runtime.h>
#include <hip/hip_bf16.h>

#define N_NODES 50000
#define N_PAD 50048 /* 391*128 */
#define NBY 391
#define N_EDGES 400000
#define EP (N_EDGES + N_NODES) /* 450000 with self loops */
#define N_GRAPHS 256
#define EMB 64
#define HID 128
#define HEADS 4
#define GDIM 256
#define NUM_CLASSES 20
#define EPS_BN 1e-5f
#define NEG_SLOPE 0.2f
#define NB_AGG 2048

typedef __attribute__((ext_vector_type(8))) short short8;
typedef __attribute__((ext_vector_type(4))) float f32x4;

#define GLD(g, l)                                                              \
    __builtin_amdgcn_global_load_lds(                                          \
        (const __attribute__((address_space(1))) void*)(g),                    \
        (__attribute__((address_space(3))) void*)(l), 16, 0, 0)

__device__ __forceinline__ unsigned short f2b(float x) {
    union { float f; unsigned u; } a; a.f = x;
    unsigned r = a.u + 0x7FFF + ((a.u >> 16) & 1);
    return (unsigned short)(r >> 16);
}
__device__ __forceinline__ float b2f(unsigned short h) {
    union { unsigned u; float f; } a; a.u = (unsigned)h << 16;
    return a.f;
}

// ---------------- node features ----------------
__global__ void k_node_init(const int* __restrict__ x, const float* __restrict__ depth,
                            const float* __restrict__ emb_table, const float* __restrict__ dw,
                            const float* __restrict__ db, float* __restrict__ h) {
    int i = blockIdx.x * blockDim.x + threadIdx.x;
    if (i >= N_NODES * EMB) return;
    int n = i >> 6, c = i & 63;
    h[i] = emb_table[x[n] * EMB + c] + depth[n] * dw[c] + db[c];
}

// ---------------- CSR build ----------------
__global__ void k_deg(const int* __restrict__ ei, int* __restrict__ deg) {
    int e = blockIdx.x * blockDim.x + threadIdx.x;
    if (e >= EP) return;
    int dst = (e < N_EDGES) ? ei[N_EDGES + e] : (e - N_EDGES);
    atomicAdd(&deg[dst], 1);
}

__global__ void k_scanA(const int* __restrict__ deg, int* __restrict__ incl, int* __restrict__ bsums) {
    __shared__ int sh[1024];
    int t = threadIdx.x;
    int i = blockIdx.x * 1024 + t;
    int v = (i < N_NODES) ? deg[i] : 0;
    int xv = v;
    sh[t] = xv;
    __syncthreads();
    for (int off = 1; off < 1024; off <<= 1) {
        int y = (t >= off) ? sh[t - off] : 0;
        __syncthreads();
        xv += y;
        sh[t] = xv;
        __syncthreads();
    }
    if (i < N_NODES) incl[i] = xv;
    if (t == 1023) bsums[blockIdx.x] = xv;
}

__global__ void k_scanB(int* __restrict__ bsums, int nb) {
    if (threadIdx.x == 0 && blockIdx.x == 0) {
        int run = 0;
        for (int b = 0; b < nb; b++) { int v = bsums[b]; bsums[b] = run; run += v; }
    }
}

__global__ void k_scanC(const int* __restrict__ incl, const int* __restrict__ deg,
                        const int* __restrict__ bsums, int* __restrict__ offs) {
    int i = blockIdx.x * blockDim.x + threadIdx.x;
    if (i < N_NODES) offs[i] = incl[i] - deg[i] + bsums[i >> 10];
    if (i == 0) offs[N_NODES] = EP;
}

__global__ void k_scatter(const int* __restrict__ ei, const int* __restrict__ offs,
                          int* __restrict__ cnt, int* __restrict__ csr) {
    int e = blockIdx.x * blockDim.x + threadIdx.x;
    if (e >= EP) return;
    int src, dst;
    if (e < N_EDGES) { src = ei[e]; dst = ei[N_EDGES + e]; }
    else { src = e - N_EDGES; dst = src; }
    int pos = atomicAdd(&cnt[dst], 1);
    csr[offs[dst] + pos] = src;
}

// ---------------- split fp32 -> bf16 hi/lo (weights; + zero BN accumulator) ----------------
__global__ __launch_bounds__(256) void k_split(const float* __restrict__ in,
                                               unsigned short* __restrict__ hi,
                                               unsigned short* __restrict__ lo,
                                               float* __restrict__ bnz,
                                               int total4, int real) {
    if (blockIdx.x == 0 && bnz) {
        for (int tt = threadIdx.x; tt < 1024; tt += 256) bnz[tt] = 0.f;
    }
    int i = blockIdx.x * blockDim.x + threadIdx.x;
    if (i >= total4) return;
    int f = i * 4;
    float4 v = make_float4(0.f, 0.f, 0.f, 0.f);
    if (f < real) v = *(const float4*)(in + f);
    ushort4 h, l;
    h.x = f2b(v.x); l.x = f2b(v.x - b2f(h.x));
    h.y = f2b(v.y); l.y = f2b(v.y - b2f(h.y));
    h.z = f2b(v.z); l.z = f2b(v.z - b2f(h.z));
    h.w = f2b(v.w); l.w = f2b(v.w - b2f(h.w));
    *(ushort4*)(hi + f) = h;
    *(ushort4*)(lo + f) = l;
}

// ---------------- in-place BN+ELU on hi/lo (scale computed inline from sums) ----------------
__global__ __launch_bounds__(256) void k_bnsplit(unsigned short* __restrict__ hi,
                                                 unsigned short* __restrict__ lo,
                                                 const float* __restrict__ sums,
                                                 const float* __restrict__ gamma,
                                                 const float* __restrict__ beta,
                                                 int M, int total4) {
    int i = blockIdx.x * blockDim.x + threadIdx.x;
    if (i >= total4) return;
    int f = i * 4;
    int c = f & (M - 1);
    float4 s4 = *(const float4*)(sums + c);
    float4 q4 = *(const float4*)(sums + M + c);
    float4 g4 = *(const float4*)(gamma + c);
    float4 be4 = *(const float4*)(beta + c);
    const float invN = 1.f / (float)N_NODES;
    float4 sc, sh;
    {
        float m = s4.x * invN; float var = q4.x * invN - m * m;
        sc.x = g4.x * __frsqrt_rn(var + EPS_BN); sh.x = be4.x - m * sc.x;
        m = s4.y * invN; var = q4.y * invN - m * m;
        sc.y = g4.y * __frsqrt_rn(var + EPS_BN); sh.y = be4.y - m * sc.y;
        m = s4.z * invN; var = q4.z * invN - m * m;
        sc.z = g4.z * __frsqrt_rn(var + EPS_BN); sh.z = be4.z - m * sc.z;
        m = s4.w * invN; var = q4.w * invN - m * m;
        sc.w = g4.w * __frsqrt_rn(var + EPS_BN); sh.w = be4.w - m * sc.w;
    }
    ushort4 h4 = *(const ushort4*)(hi + f);
    ushort4 l4 = *(const ushort4*)(lo + f);
    float4 v;
    v.x = b2f(h4.x) + b2f(l4.x);
    v.y = b2f(h4.y) + b2f(l4.y);
    v.z = b2f(h4.z) + b2f(l4.z);
    v.w = b2f(h4.w) + b2f(l4.w);
    float x;
    x = v.x * sc.x + sh.x; v.x = x > 0.f ? x : expm1f(x);
    x = v.y * sc.y + sh.y; v.y = x > 0.f ? x : expm1f(x);
    x = v.z * sc.z + sh.z; v.z = x > 0.f ? x : expm1f(x);
    x = v.w * sc.w + sh.w; v.w = x > 0.f ? x : expm1f(x);
    ushort4 h, l;
    h.x = f2b(v.x); l.x = f2b(v.x - b2f(h.x));
    h.y = f2b(v.y); l.y = f2b(v.y - b2f(h.y));
    h.z = f2b(v.z); l.z = f2b(v.z - b2f(h.z));
    h.w = f2b(v.w); l.w = f2b(v.w - b2f(h.w));
    *(ushort4*)(hi + f) = h;
    *(ushort4*)(lo + f) = l;
}

// ---------------- layer-0 h-space helpers ----------------
__global__ void k_wproj(const float* __restrict__ W0, const float* __restrict__ as_,
                        const float* __restrict__ ad_, float* __restrict__ wtil) {
    int t = threadIdx.x;  // 256
    int h = t >> 6, k = t & 63;
    float ss = 0.f, sd = 0.f;
    for (int c = 0; c < 128; c++) {
        float w = W0[(size_t)(h * 128 + c) * 64 + k];
        ss += w * as_[h * 128 + c];
        sd += w * ad_[h * 128 + c];
    }
    wtil[t] = ss;
    wtil[256 + t] = sd;
}

__global__ __launch_bounds__(256) void k_al0(const float* __restrict__ h0,
                                             const float* __restrict__ wtil,
                                             float* __restrict__ als, float* __restrict__ ald,
                                             float* __restrict__ bnz) {
    if (blockIdx.x == 0) {
        for (int t = threadIdx.x; t < 1024; t += 256) bnz[t] = 0.f;
    }
    int wid = threadIdx.x >> 6, lane = threadIdx.x & 63;
    int n = blockIdx.x * 4 + wid;
    if (n >= N_NODES) return;
    float v = h0[(size_t)n * 64 + lane];
#pragma unroll
    for (int h = 0; h < 4; h++) {
        float ps = v * wtil[h * 64 + lane];
        float pd = v * wtil[256 + h * 64 + lane];
        for (int off = 32; off; off >>= 1) {
            ps += __shfl_xor(ps, off);
            pd += __shfl_xor(pd, off);
        }
        if (lane == 0) { als[n * 4 + h] = ps; ald[n * 4 + h] = pd; }
    }
}

// layer-0 aggregate in h-space: QUARTER-WAVE per node (4 nodes/wave in lockstep).
__global__ __launch_bounds__(256) void k_agg0(const float* __restrict__ h0,
                                              const float* __restrict__ als,
                                              const float* __restrict__ ald_g,
                                              const int* __restrict__ offs,
                                              const int* __restrict__ csr,
                                              unsigned short* __restrict__ outh,
                                              unsigned short* __restrict__ outl) {
    const int lane = threadIdx.x & 63;
    const int wwid = threadIdx.x >> 6;
    const int q = lane >> 4, l = lane & 15;
    const int gw = blockIdx.x * 4 + wwid;
    const int stride = gridDim.x * 16;
    for (int n = gw * 4 + q; n < N_NODES; n += stride) {
        int s0 = offs[n], s1 = offs[n + 1];
        float aldl = (l < 4) ? ald_g[n * 4 + l] : 0.f;
        float acc[4][4] = {};
        float den[4] = {};
        int e = s0;
        for (; e + 2 <= s1; e += 2) {
            int srcA = csr[e], srcB = csr[e + 1];
            float wA = 0.f, wB = 0.f;
            if (l < 4) {
                float a1 = als[srcA * 4 + l] + aldl;
                a1 = a1 > 0.f ? a1 : NEG_SLOPE * a1;
                wA = expf(a1);
                float a2 = als[srcB * 4 + l] + aldl;
                a2 = a2 > 0.f ? a2 : NEG_SLOPE * a2;
                wB = expf(a2);
            }
            float4 vA = *(const float4*)(h0 + (size_t)srcA * 64 + l * 4);
            float4 vB = *(const float4*)(h0 + (size_t)srcB * 64 + l * 4);
#pragma unroll
            for (int h = 0; h < 4; h++) {
                float whA = __shfl(wA, q * 16 + h);
                float whB = __shfl(wB, q * 16 + h);
                den[h] += whA + whB;
                acc[h][0] += whA * vA.x + whB * vB.x;
                acc[h][1] += whA * vA.y + whB * vB.y;
                acc[h][2] += whA * vA.z + whB * vB.z;
                acc[h][3] += whA * vA.w + whB * vB.w;
            }
        }
        for (; e < s1; e++) {
            int src = csr[e];
            float w = 0.f;
            if (l < 4) {
                float a1 = als[src * 4 + l] + aldl;
                a1 = a1 > 0.f ? a1 : NEG_SLOPE * a1;
                w = expf(a1);
            }
            float4 v = *(const float4*)(h0 + (size_t)src * 64 + l * 4);
#pragma unroll
            for (int h = 0; h < 4; h++) {
                float wh = __shfl(w, q * 16 + h);
                den[h] += wh;
                acc[h][0] += wh * v.x;
                acc[h][1] += wh * v.y;
                acc[h][2] += wh * v.z;
                acc[h][3] += wh * v.w;
            }
        }
#pragma unroll
        for (int h = 0; h < 4; h++) {
            float id = 1.f / den[h];
            float o0 = acc[h][0] * id, o1 = acc[h][1] * id;
            float o2 = acc[h][2] * id, o3 = acc[h][3] * id;
            ushort4 hh, ll;
            hh.x = f2b(o0); ll.x = f2b(o0 - b2f(hh.x));
            hh.y = f2b(o1); ll.y = f2b(o1 - b2f(hh.y));
            hh.z = f2b(o2); ll.z = f2b(o2 - b2f(hh.z));
            hh.w = f2b(o3); ll.w = f2b(o3 - b2f(hh.w));
            size_t idx = (size_t)n * 256 + h * 64 + l * 4;
            *(ushort4*)(outh + idx) = hh;
            *(ushort4*)(outl + idx) = ll;
        }
    }
}

// layer-0 block-diag MFMA GEMM + fused BN-stats epilogue
__global__ __launch_bounds__(256) void k_gemm0h(const unsigned short* __restrict__ Ahh,
                                                const unsigned short* __restrict__ Ahl,
                                                const unsigned short* __restrict__ Wh,
                                                const unsigned short* __restrict__ Wl,
                                                const float* __restrict__ bias,
                                                unsigned short* __restrict__ outh,
                                                unsigned short* __restrict__ outl,
                                                float* __restrict__ bnacc) {
    __shared__ short8 sAh[512], sAl[512], sWh[512], sWl[512];
    const int nbx = gridDim.x;
    const int d = blockIdx.y * nbx + blockIdx.x;
    const int by = (d / (8 * nbx)) * 8 + (d & 7);
    const int bx = (d >> 3) % nbx;
    if (by >= NBY) return;
    const int hd = bx;
    const int t = threadIdx.x;
    const int lane = t & 63;
    const int wid = t >> 6;
    const int wm = wid >> 1, wn = wid & 1;
    const int r0 = by * 128;
    const int l15 = lane & 15, quad = lane >> 4;
    f32x4 acc[4][4] = {};
    for (int kb = 0; kb < 64; kb += 32) {
#pragma unroll
        for (int r = 0; r < 2; r++) {
            int c = r * 256 + t;
            int row = c >> 2, q = c & 3;
            size_t gA = ((size_t)(r0 + row) * 256 + hd * 64 + kb) * 2 + q * 16;
            size_t gW = ((size_t)(hd * 128 + row) * 64 + kb) * 2 + q * 16;
            GLD((const char*)Ahh + gA, (char*)sAh + c * 16);
            GLD((const char*)Ahl + gA, (char*)sAl + c * 16);
            GLD((const char*)Wh + gW, (char*)sWh + c * 16);
            GLD((const char*)Wl + gW, (char*)sWl + c * 16);
        }
        __syncthreads();
        short8 a_h[4], a_l[4], w_h[4], w_l[4];
#pragma unroll
        for (int i = 0; i < 4; i++) {
            int ra = (wm * 64 + i * 16 + l15) * 4 + quad;
            int rw = (wn * 64 + i * 16 + l15) * 4 + quad;
            a_h[i] = sAh[ra]; a_l[i] = sAl[ra];
            w_h[i] = sWh[rw]; w_l[i] = sWl[rw];
        }
#pragma unroll
        for (int i = 0; i < 4; i++)
#pragma unroll
            for (int j = 0; j < 4; j++) {
                acc[i][j] = __builtin_amdgcn_mfma_f32_16x16x32_bf16(a_h[i], w_h[j], acc[i][j], 0, 0, 0);
                acc[i][j] = __builtin_amdgcn_mfma_f32_16x16x32_bf16(a_h[i], w_l[j], acc[i][j], 0, 0, 0);
                acc[i][j] = __builtin_amdgcn_mfma_f32_16x16x32_bf16(a_l[i], w_h[j], acc[i][j], 0, 0, 0);
            }
        __syncthreads();
    }
    float colsum[4] = {}, colsq[4] = {};
#pragma unroll
    for (int i = 0; i < 4; i++) {
        int gr = r0 + wm * 64 + i * 16 + quad * 4;
#pragma unroll
        for (int j = 0; j < 4; j++) {
            int gc = hd * 128 + wn * 64 + j * 16 + l15;
            float bv = bias[gc];
#pragma unroll
            for (int rg = 0; rg < 4; rg++) {
                int rr = gr + rg;
                if (rr < N_NODES) {
                    float o = acc[i][j][rg] + bv;
                    unsigned short hh = f2b(o);
                    size_t idx = (size_t)rr * 512 + gc;
                    outh[idx] = hh;
                    outl[idx] = f2b(o - b2f(hh));
                    colsum[j] += o;
                    colsq[j] += o * o;
                }
            }
        }
    }
#pragma unroll
    for (int j = 0; j < 4; j++) {
        colsum[j] += __shfl_xor(colsum[j], 16);
        colsum[j] += __shfl_xor(colsum[j], 32);
        colsq[j] += __shfl_xor(colsq[j], 16);
        colsq[j] += __shfl_xor(colsq[j], 32);
    }
    float* sS = (float*)sAh;
    float* sQ = (float*)sAl;
    __syncthreads();
    if (quad == 0) {
#pragma unroll
        for (int j = 0; j < 4; j++) {
            int c = wn * 64 + j * 16 + l15;
            sS[c * 2 + wm] = colsum[j];
            sQ[c * 2 + wm] = colsq[j];
        }
    }
    __syncthreads();
    if (t < 128) {
        atomicAdd(bnacc + hd * 128 + t, sS[t * 2] + sS[t * 2 + 1]);
        atomicAdd(bnacc + 512 + hd * 128 + t, sQ[t * 2] + sQ[t * 2 + 1]);
    }
}

// ---------------- bf16 hi/lo MFMA GEMM + fused attention-logit epilogue ----------------
__global__ __launch_bounds__(256) void k_gemm_mfma(const unsigned short* __restrict__ Ah,
                                                   const unsigned short* __restrict__ Al,
                                                   const unsigned short* __restrict__ Wh,
                                                   const unsigned short* __restrict__ Wl,
                                                   const float* __restrict__ a_src,
                                                   const float* __restrict__ a_dst,
                                                   float* __restrict__ als_g,
                                                   float* __restrict__ ald_g,
                                                   float* __restrict__ out,
                                                   int K, int M, int heads) {
    __shared__ short8 sAh[512], sAl[512], sWh[512], sWl[512];
    const int nbx = gridDim.x;
    const int d = blockIdx.y * nbx + blockIdx.x;
    const int by = (d / (8 * nbx)) * 8 + (d & 7);
    const int bx = (d >> 3) % nbx;
    if (by >= NBY) return;
    const int t = threadIdx.x;
    const int lane = t & 63;
    const int wid = t >> 6;
    const int wm = wid >> 1, wn = wid & 1;
    const int r0 = by * 128, c0 = bx * 128;
    const int l15 = lane & 15, quad = lane >> 4;
    f32x4 acc[4][4] = {};
    for (int kb = 0; kb < K; kb += 32) {
#pragma unroll
        for (int r = 0; r < 2; r++) {
            int c = r * 256 + t;
            int row = c >> 2, q = c & 3;
            size_t gA = ((size_t)(r0 + row) * K + kb) * 2 + q * 16;
            size_t gW = ((size_t)(c0 + row) * K + kb) * 2 + q * 16;
            GLD((const char*)Ah + gA, (char*)sAh + c * 16);
            GLD((const char*)Al + gA, (char*)sAl + c * 16);
            GLD((const char*)Wh + gW, (char*)sWh + c * 16);
            GLD((const char*)Wl + gW, (char*)sWl + c * 16);
        }
        __syncthreads();
        short8 a_h[4], a_l[4], w_h[4], w_l[4];
#pragma unroll
        for (int i = 0; i < 4; i++) {
            int ra = (wm * 64 + i * 16 + l15) * 4 + quad;
            int rw = (wn * 64 + i * 16 + l15) * 4 + quad;
            a_h[i] = sAh[ra]; a_l[i] = sAl[ra];
            w_h[i] = sWh[rw]; w_l[i] = sWl[rw];
        }
#pragma unroll
        for (int i = 0; i < 4; i++)
#pragma unroll
            for (int j = 0; j < 4; j++) {
                acc[i][j] = __builtin_amdgcn_mfma_f32_16x16x32_bf16(a_h[i], w_h[j], acc[i][j], 0, 0, 0);
                acc[i][j] = __builtin_amdgcn_mfma_f32_16x16x32_bf16(a_h[i], w_l[j], acc[i][j], 0, 0, 0);
                acc[i][j] = __builtin_amdgcn_mfma_f32_16x16x32_bf16(a_l[i], w_h[j], acc[i][j], 0, 0, 0);
            }
        __syncthreads();
    }
#pragma unroll
    for (int i = 0; i < 4; i++) {
        int gr = r0 + wm * 64 + i * 16 + quad * 4;
#pragma unroll
        for (int j = 0; j < 4; j++) {
            int gc = c0 + wn * 64 + j * 16 + l15;
#pragma unroll
            for (int rg = 0; rg < 4; rg++) {
                int rr = gr + rg;
                if (rr < N_NODES) out[(size_t)rr * M + gc] = acc[i][j][rg];
            }
        }
    }
    const int hd = bx;
    float ps[4][4] = {}, pd[4][4] = {};
#pragma unroll
    for (int j = 0; j < 4; j++) {
        int ch = wn * 64 + j * 16 + l15;
        float av = a_src[hd * 128 + ch];
        float dv = a_dst[hd * 128 + ch];
#pragma unroll
        for (int i = 0; i < 4; i++)
#pragma unroll
            for (int rg = 0; rg < 4; rg++) {
                ps[i][rg] += acc[i][j][rg] * av;
                pd[i][rg] += acc[i][j][rg] * dv;
            }
    }
#pragma unroll
    for (int m = 1; m < 16; m <<= 1)
#pragma unroll
        for (int i = 0; i < 4; i++)
#pragma unroll
            for (int rg = 0; rg < 4; rg++) {
                ps[i][rg] += __shfl_xor(ps[i][rg], m);
                pd[i][rg] += __shfl_xor(pd[i][rg], m);
            }
    float* sS = (float*)sAh;
    float* sD = (float*)sAl;
    if (l15 == 0) {
#pragma unroll
        for (int i = 0; i < 4; i++)
#pragma unroll
            for (int rg = 0; rg < 4; rg++) {
                int ri = wm * 64 + i * 16 + quad * 4 + rg;
                sS[ri * 2 + wn] = ps[i][rg];
                sD[ri * 2 + wn] = pd[i][rg];
            }
    }
    __syncthreads();
    if (t < 128) {
        int row = r0 + t;
        if (row < N_NODES) {
            als_g[row * heads + hd] = sS[t * 2] + sS[t * 2 + 1];
            ald_g[row * heads + hd] = sD[t * 2] + sD[t * 2 + 1];
        }
    }
}

// ---------------- fp32 GEMM fallback ----------------
#define BM 128
#define BN 128
#define BK 16
__global__ __launch_bounds__(256) void k_gemm(const float* __restrict__ Ain,
                                              const float* __restrict__ W,
                                              float* __restrict__ out,
                                              int Nrows, int K, int M) {
    __shared__ float As[BK][BM + 4];
    __shared__ float Ws[BK][BN + 4];
    int r0 = blockIdx.y * BM, c0 = blockIdx.x * BN;
    int t = threadIdx.x;
    int tx = t & 15, ty = t >> 4;
    float acc[8][8] = {};
    for (int kb = 0; kb < K; kb += BK) {
#pragma unroll
        for (int i = 0; i < 2; i++) {
            int lin = t + i * 256;
            int row = lin >> 2;
            int kq = (lin & 3) * 4;
            int gr = r0 + row;
            float4 v = make_float4(0.f, 0.f, 0.f, 0.f);
            if (gr < Nrows) v = *(const float4*)(Ain + (size_t)gr * K + kb + kq);
            As[kq + 0][row] = v.x; As[kq + 1][row] = v.y; As[kq + 2][row] = v.z; As[kq + 3][row] = v.w;
        }
#pragma unroll
        for (int i = 0; i < 2; i++) {
            int lin = t + i * 256;
            int row = lin >> 2;
            int kq = (lin & 3) * 4;
            int gm = c0 + row;
            float4 v = *(const float4*)(W + (size_t)gm * K + kb + kq);
            Ws[kq + 0][row] = v.x; Ws[kq + 1][row] = v.y; Ws[kq + 2][row] = v.z; Ws[kq + 3][row] = v.w;
        }
        __syncthreads();
#pragma unroll
        for (int k = 0; k < BK; k++) {
            float a[8], b[8];
#pragma unroll
            for (int i = 0; i < 4; i++) {
                float2 v = *(const float2*)&As[k][ty * 2 + 32 * i];
                a[2 * i] = v.x; a[2 * i + 1] = v.y;
            }
#pragma unroll
            for (int j = 0; j < 4; j++) {
                float2 v = *(const float2*)&Ws[k][tx * 2 + 32 * j];
                b[2 * j] = v.x; b[2 * j + 1] = v.y;
            }
#pragma unroll
            for (int i = 0; i < 8; i++)
#pragma unroll
                for (int j = 0; j < 8; j++) acc[i][j] += a[i] * b[j];
        }
        __syncthreads();
    }
#pragma unroll
    for (int i = 0; i < 8; i++) {
        int row = r0 + 32 * (i >> 1) + ty * 2 + (i & 1);
        if (row >= Nrows) continue;
#pragma unroll
        for (int j = 0; j < 4; j++) {
            int col = c0 + 32 * j + tx * 2;
            *(float2*)(out + (size_t)row * M + col) = make_float2(acc[i][2 * j], acc[i][2 * j + 1]);
        }
    }
}

// ---------------- attention logits (fallback path only; + zero BN acc) ----------------
__global__ __launch_bounds__(256) void k_al(const float* __restrict__ xf,
                                            const float* __restrict__ a_src,
                                            const float* __restrict__ a_dst,
                                            float* __restrict__ als, float* __restrict__ ald,
                                            float* __restrict__ bn_zero,
                                            int M, int heads) {
    if (blockIdx.x == 0) {
        for (int t = threadIdx.x; t < 1024; t += 256) bn_zero[t] = 0.f;
    }
    int wid = threadIdx.x >> 6, lane = threadIdx.x & 63;
    int n = blockIdx.x * 4 + wid;
    if (n >= N_NODES) return;
    for (int h = 0; h < heads; h++) {
        float x0 = xf[(size_t)n * M + h * 128 + lane];
        float x1 = xf[(size_t)n * M + h * 128 + 64 + lane];
        float ps = x0 * a_src[h * 128 + lane] + x1 * a_src[h * 128 + 64 + lane];
        float pd = x0 * a_dst[h * 128 + lane] + x1 * a_dst[h * 128 + 64 + lane];
        for (int off = 32; off; off >>= 1) {
            ps += __shfl_xor(ps, off);
            pd += __shfl_xor(pd, off);
        }
        if (lane == 0) { als[n * heads + h] = ps; ald[n * heads + h] = pd; }
    }
}

// ---------------- segment softmax aggregation (shift-free) + fused BN stats ----------------
// Round-8 structure: per 64-edge chunk weights computed lane-parallel and staged
// to per-wave LDS; gather loop unrolled x4 (8 float4 loads in flight).
template <int M, int NH, bool HL>
__global__ __launch_bounds__(256) void k_aggregate(const float* __restrict__ xf,
                                                   const float* __restrict__ als,
                                                   const float* __restrict__ ald_g,
                                                   const int* __restrict__ offs,
                                                   const int* __restrict__ csr,
                                                   const float* __restrict__ bias,
                                                   float* __restrict__ out_f,
                                                   unsigned short* __restrict__ out_h,
                                                   unsigned short* __restrict__ out_l,
                                                   float* __restrict__ bnacc) {
    __shared__ float pool[4][2 * M];
    const int wid = threadIdx.x >> 6, lane = threadIdx.x & 63;
    int* s_src = (int*)&pool[wid][0];
    float* s_w = &pool[wid][64];
    const int gw = blockIdx.x * 4 + wid;
    const int nw = gridDim.x * 4;
    if constexpr (M == 512) {
        const int c0 = lane * 4, c1 = 256 + lane * 4;
        const int h0 = lane >> 5;
        const int h1 = 2 + (lane >> 5);
        const float4 bias0 = *(const float4*)(bias + c0);
        const float4 bias1 = *(const float4*)(bias + c1);
        float bns[8] = {}, bnq[8] = {};
        for (int n = gw; n < N_NODES; n += nw) {
            int s0 = offs[n], s1 = offs[n + 1];
            float4 aldv = *(const float4*)(ald_g + n * 4);
            float4 a0 = make_float4(0.f, 0.f, 0.f, 0.f);
            float4 a1 = make_float4(0.f, 0.f, 0.f, 0.f);
            float den0 = 0.f, den1 = 0.f;
            for (int base = s0; base < s1; base += 64) {
                int j = base + lane;
                int srcj = 0;
                float4 alv = make_float4(0.f, 0.f, 0.f, 0.f);
                if (j < s1) {
                    srcj = csr[j];
                    alv = *(const float4*)(als + srcj * 4);
                }
                float e0 = alv.x + aldv.x; e0 = e0 > 0.f ? e0 : NEG_SLOPE * e0;
                float e1 = alv.y + aldv.y; e1 = e1 > 0.f ? e1 : NEG_SLOPE * e1;
                float e2 = alv.z + aldv.z; e2 = e2 > 0.f ? e2 : NEG_SLOPE * e2;
                float e3 = alv.w + aldv.w; e3 = e3 > 0.f ? e3 : NEG_SLOPE * e3;
                s_src[lane] = srcj;
                s_w[0 * 64 + lane] = expf(e0);
                s_w[1 * 64 + lane] = expf(e1);
                s_w[2 * 64 + lane] = expf(e2);
                s_w[3 * 64 + lane] = expf(e3);
                int cend = min(64, s1 - base);
                int e = 0;
                for (; e + 4 <= cend; e += 4) {
                    int sA = s_src[e], sB = s_src[e + 1];
                    int sC = s_src[e + 2], sD = s_src[e + 3];
                    float wAl = s_w[h0 * 64 + e],     wAh = s_w[h1 * 64 + e];
                    float wBl = s_w[h0 * 64 + e + 1], wBh = s_w[h1 * 64 + e + 1];
                    float wCl = s_w[h0 * 64 + e + 2], wCh = s_w[h1 * 64 + e + 2];
                    float wDl = s_w[h0 * 64 + e + 3], wDh = s_w[h1 * 64 + e + 3];
                    const float* rA = xf + (size_t)sA * 512;
                    const float* rB = xf + (size_t)sB * 512;
                    const float* rC = xf + (size_t)sC * 512;
                    const float* rD = xf + (size_t)sD * 512;
                    float4 vA0 = *(const float4*)(rA + c0);
                    float4 vA1 = *(const float4*)(rA + c1);
                    float4 vB0 = *(const float4*)(rB + c0);
                    float4 vB1 = *(const float4*)(rB + c1);
                    float4 vC0 = *(const float4*)(rC + c0);
                    float4 vC1 = *(const float4*)(rC + c1);
                    float4 vD0 = *(const float4*)(rD + c0);
                    float4 vD1 = *(const float4*)(rD + c1);
                    den0 += wAl + wBl + wCl + wDl;
                    den1 += wAh + wBh + wCh + wDh;
                    a0.x += wAl * vA0.x + wBl * vB0.x + wCl * vC0.x + wDl * vD0.x;
                    a0.y += wAl * vA0.y + wBl * vB0.y + wCl * vC0.y + wDl * vD0.y;
                    a0.z += wAl * vA0.z + wBl * vB0.z + wCl * vC0.z + wDl * vD0.z;
                    a0.w += wAl * vA0.w + wBl * vB0.w + wCl * vC0.w + wDl * vD0.w;
                    a1.x += wAh * vA1.x + wBh * vB1.x + wCh * vC1.x + wDh * vD1.x;
                    a1.y += wAh * vA1.y + wBh * vB1.y + wCh * vC1.y + wDh * vD1.y;
                    a1.z += wAh * vA1.z + wBh * vB1.z + wCh * vC1.z + wDh * vD1.z;
                    a1.w += wAh * vA1.w + wBh * vB1.w + wCh * vC1.w + wDh * vD1.w;
                }
                for (; e < cend; e++) {
                    int src = s_src[e];
                    float wA = s_w[h0 * 64 + e];
                    float wB = s_w[h1 * 64 + e];
                    const float* row = xf + (size_t)src * 512;
                    float4 v0 = *(const float4*)(row + c0);
                    float4 v1 = *(const float4*)(row + c1);
                    den0 += wA; den1 += wB;
                    a0.x += wA * v0.x; a0.y += wA * v0.y; a0.z += wA * v0.z; a0.w += wA * v0.w;
                    a1.x += wB * v1.x; a1.y += wB * v1.y; a1.z += wB * v1.z; a1.w += wB * v1.w;
                }
            }
            float id0 = 1.f / den0, id1 = 1.f / den1;
            float4 o0, o1;
            o0.x = a0.x * id0 + bias0.x; o0.y = a0.y * id0 + bias0.y;
            o0.z = a0.z * id0 + bias0.z; o0.w = a0.w * id0 + bias0.w;
            o1.x = a1.x * id1 + bias1.x; o1.y = a1.y * id1 + bias1.y;
            o1.z = a1.z * id1 + bias1.z; o1.w = a1.w * id1 + bias1.w;
            size_t f0 = (size_t)n * 512 + c0, f1 = (size_t)n * 512 + c1;
            if constexpr (HL) {
                ushort4 h4, l4;
                h4.x = f2b(o0.x); l4.x = f2b(o0.x - b2f(h4.x));
                h4.y = f2b(o0.y); l4.y = f2b(o0.y - b2f(h4.y));
                h4.z = f2b(o0.z); l4.z = f2b(o0.z - b2f(h4.z));
                h4.w = f2b(o0.w); l4.w = f2b(o0.w - b2f(h4.w));
                *(ushort4*)(out_h + f0) = h4;
                *(ushort4*)(out_l + f0) = l4;
                h4.x = f2b(o1.x); l4.x = f2b(o1.x - b2f(h4.x));
                h4.y = f2b(o1.y); l4.y = f2b(o1.y - b2f(h4.y));
                h4.z = f2b(o1.z); l4.z = f2b(o1.z - b2f(h4.z));
                h4.w = f2b(o1.w); l4.w = f2b(o1.w - b2f(h4.w));
                *(ushort4*)(out_h + f1) = h4;
                *(ushort4*)(out_l + f1) = l4;
            } else {
                *(float4*)(out_f + f0) = o0;
                *(float4*)(out_f + f1) = o1;
            }
            bns[0] += o0.x; bnq[0] += o0.x * o0.x;
            bns[1] += o0.y; bnq[1] += o0.y * o0.y;
            bns[2] += o0.z; bnq[2] += o0.z * o0.z;
            bns[3] += o0.w; bnq[3] += o0.w * o0.w;
            bns[4] += o1.x; bnq[4] += o1.x * o1.x;
            bns[5] += o1.y; bnq[5] += o1.y * o1.y;
            bns[6] += o1.z; bnq[6] += o1.z * o1.z;
            bns[7] += o1.w; bnq[7] += o1.w * o1.w;
        }
#pragma unroll
        for (int k = 0; k < 4; k++) {
            pool[wid][c0 + k] = bns[k];
            pool[wid][c1 + k] = bns[4 + k];
            pool[wid][512 + c0 + k] = bnq[k];
            pool[wid][512 + c1 + k] = bnq[4 + k];
        }
        __syncthreads();
        for (int t = threadIdx.x; t < 1024; t += 256)
            atomicAdd(bnacc + t, pool[0][t] + pool[1][t] + pool[2][t] + pool[3][t]);
    } else {  // M == 128, NH == 1
        const int c = lane * 2;
        const float2 biasv = *(const float2*)(bias + c);
        float bns0 = 0.f, bns1 = 0.f, bnq0 = 0.f, bnq1 = 0.f;
        for (int n = gw; n < N_NODES; n += nw) {
            int s0 = offs[n], s1 = offs[n + 1];
            float aldv = ald_g[n];
            float2 a = make_float2(0.f, 0.f);
            float den = 0.f;
            for (int base = s0; base < s1; base += 64) {
                int j = base + lane;
                int srcj = 0;
                float alv = 0.f;
                if (j < s1) { srcj = csr[j]; alv = als[srcj]; }
                float e0 = alv + aldv;
                e0 = e0 > 0.f ? e0 : NEG_SLOPE * e0;
                s_src[lane] = srcj;
                s_w[lane] = expf(e0);
                int cend = min(64, s1 - base);
                int e = 0;
                for (; e + 4 <= cend; e += 4) {
                    int sA = s_src[e], sB = s_src[e + 1];
                    int sC = s_src[e + 2], sD = s_src[e + 3];
                    float wA = s_w[e],     wB = s_w[e + 1];
                    float wC = s_w[e + 2], wD = s_w[e + 3];
                    float2 vA = *(const float2*)(xf + (size_t)sA * 128 + c);
                    float2 vB = *(const float2*)(xf + (size_t)sB * 128 + c);
                    float2 vC = *(const float2*)(xf + (size_t)sC * 128 + c);
                    float2 vD = *(const float2*)(xf + (size_t)sD * 128 + c);
                    den += wA + wB + wC + wD;
                    a.x += wA * vA.x + wB * vB.x + wC * vC.x + wD * vD.x;
                    a.y += wA * vA.y + wB * vB.y + wC * vC.y + wD * vD.y;
                }
                for (; e < cend; e++) {
                    int src = s_src[e];
                    float w = s_w[e];
                    float2 v = *(const float2*)(xf + (size_t)src * 128 + c);
                    den += w;
                    a.x += w * v.x; a.y += w * v.y;
                }
            }
            float id = 1.f / den;
            float ox = a.x * id + biasv.x;
            float oy = a.y * id + biasv.y;
            out_f[(size_t)n * 128 + c] = ox;
            out_f[(size_t)n * 128 + c + 1] = oy;
            bns0 += ox; bnq0 += ox * ox;
            bns1 += oy; bnq1 += oy * oy;
        }
        pool[wid][c] = bns0; pool[wid][c + 1] = bns1;
        pool[wid][128 + c] = bnq0; pool[wid][128 + c + 1] = bnq1;
        __syncthreads();
        for (int t = threadIdx.x; t < 256; t += 256)
            atomicAdd(bnacc + t, pool[0][t] + pool[1][t] + pool[2][t] + pool[3][t]);
    }
}

// ---------------- BN+ELU apply, fp32 (scale computed inline from sums) ----------------
__global__ __launch_bounds__(256) void k_bn_apply(float* __restrict__ h,
                                                  const float* __restrict__ sums,
                                                  const float* __restrict__ gamma,
                                                  const float* __restrict__ beta,
                                                  int M, int total4) {
    int i = blockIdx.x * blockDim.x + threadIdx.x;
    if (i >= total4) return;
    int f = i * 4;
    int c = f & (M - 1);
    float4 s4 = *(const float4*)(sums + c);
    float4 q4 = *(const float4*)(sums + M + c);
    float4 g4 = *(const float4*)(gamma + c);
    float4 be4 = *(const float4*)(beta + c);
    const float invN = 1.f / (float)N_NODES;
    float4 sc, sh;
    {
        float m = s4.x * invN; float var = q4.x * invN - m * m;
        sc.x = g4.x * __frsqrt_rn(var + EPS_BN); sh.x = be4.x - m * sc.x;
        m = s4.y * invN; var = q4.y * invN - m * m;
        sc.y = g4.y * __frsqrt_rn(var + EPS_BN); sh.y = be4.y - m * sc.y;
        m = s4.z * invN; var = q4.z * invN - m * m;
        sc.z = g4.z * __frsqrt_rn(var + EPS_BN); sh.z = be4.z - m * sc.z;
        m = s4.w * invN; var = q4.w * invN - m * m;
        sc.w = g4.w * __frsqrt_rn(var + EPS_BN); sh.w = be4.w - m * sc.w;
    }
    float4 v = *(float4*)(h + f);
    float x;
    x = v.x * sc.x + sh.x; v.x = x > 0.f ? x : expm1f(x);
    x = v.y * sc.y + sh.y; v.y = x > 0.f ? x : expm1f(x);
    x = v.z * sc.z + sh.z; v.z = x > 0.f ? x : expm1f(x);
    x = v.w * sc.w + sh.w; v.w = x > 0.f ? x : expm1f(x);
    *(float4*)(h + f) = v;
}

// ---------------- pooling + classifier ----------------
__global__ void k_graph_bounds(const int* __restrict__ batch, int* __restrict__ goffs) {
    int n = blockIdx.x * blockDim.x + threadIdx.x;
    if (n >= N_NODES) return;
    int b = batch[n];
    int bp = (n == 0) ? -1 : batch[n - 1];
    for (int g = bp + 1; g <= b; g++) goffs[g] = n;
    if (n == N_NODES - 1) {
        for (int g = b + 1; g <= N_GRAPHS; g++) goffs[g] = N_NODES;
    }
}

__global__ void k_pool(const float* __restrict__ h, const int* __restrict__ goffs, float* __restrict__ emb) {
    int g = blockIdx.x;
    int c = threadIdx.x;
    int s = goffs[g], e = goffs[g + 1];
    float sum = 0.f, mx = -INFINITY;
    for (int n = s; n < e; n++) {
        float v = h[(size_t)n * 128 + c];
        sum += v;
        mx = fmaxf(mx, v);
    }
    int cnt = e - s;
    emb[g * 256 + c] = sum / (float)max(cnt, 1);
    emb[g * 256 + 128 + c] = mx;
}

__global__ __launch_bounds__(256) void k_classify(const float* __restrict__ emb,
                                                  const float* __restrict__ cw1, const float* __restrict__ cb1,
                                                  const float* __restrict__ cw2, const float* __restrict__ cb2,
                                                  float* __restrict__ out) {
    __shared__ float er[256];
    __shared__ float hid[256];
    int g = blockIdx.x, t = threadIdx.x;
    er[t] = emb[g * 256 + t];
    __syncthreads();
    float acc = cb1[t];
    for (int k = 0; k < 256; k++) acc += er[k] * cw1[t * 256 + k];
    hid[t] = fmaxf(acc, 0.f);
    __syncthreads();
    if (t < NUM_CLASSES) {
        float o = cb2[t];
        for (int k = 0; k < 256; k++) o += hid[k] * cw2[t * 256 + k];
        out[g * NUM_CLASSES + t] = o;
    }
}

// ---------------- driver ----------------
extern "C" void kernel_launch(void* const* d_in, const int* in_sizes, int n_in,
                              void* d_out, int out_size, void* d_ws, size_t ws_size,
                              hipStream_t stream) {
    const int* x = (const int*)d_in[0];
    const int* ei = (const int*)d_in[1];
    const float* depth = (const float*)d_in[2];
    const int* batch = (const int*)d_in[3];
    const float* emb_table = (const float*)d_in[4];
    const float* depth_w = (const float*)d_in[5];
    const float* depth_b = (const float*)d_in[6];
    const float* W0 = (const float*)d_in[7];
    const float* as0 = (const float*)d_in[8];
    const float* ad0 = (const float*)d_in[9];
    const float* b0 = (const float*)d_in[10];
    const float* g0 = (const float*)d_in[11];
    const float* be0 = (const float*)d_in[12];
    const float* W1 = (const float*)d_in[13];
    const float* as1 = (const float*)d_in[14];
    const float* ad1 = (const float*)d_in[15];
    const float* b1 = (const float*)d_in[16];
    const float* g1 = (const float*)d_in[17];
    const float* be1 = (const float*)d_in[18];
    const float* W2 = (const float*)d_in[19];
    const float* as2 = (const float*)d_in[20];
    const float* ad2 = (const float*)d_in[21];
    const float* b2 = (const float*)d_in[22];
    const float* g2 = (const float*)d_in[23];
    const float* be2 = (const float*)d_in[24];
    const float* cw1 = (const float*)d_in[25];
    const float* cb1 = (const float*)d_in[26];
    const float* cw2 = (const float*)d_in[27];
    const float* cb2 = (const float*)d_in[28];
    float* out = (float*)d_out;

    // workspace carve — must stay <= 211,469,440 B (proven ws_size lower bound)
    size_t off = 0;
    char* base = (char*)d_ws;
    auto carve = [&](size_t bytes) -> void* {
        void* p = base + off;
        off += (bytes + 255) & ~(size_t)255;
        return p;
    };
    float* B = (float*)carve((size_t)N_NODES * 512 * 4);                     // 102.4 MB
    unsigned short* Ah = (unsigned short*)carve((size_t)N_NODES * 512 * 2);  // 51.2 MB
    unsigned short* Al = (unsigned short*)carve((size_t)N_NODES * 512 * 2);  // 51.2 MB
    unsigned short* Wh = (unsigned short*)carve((size_t)512 * 512 * 2);
    unsigned short* Wl = (unsigned short*)carve((size_t)512 * 512 * 2);
    float* als = (float*)carve((size_t)N_NODES * HEADS * 4);
    float* ald = (float*)carve((size_t)N_NODES * HEADS * 4);
    float* bn = (float*)carve(4 * 512 * 4);
    float* wtil = (float*)carve(512 * 4);
    float* emb = (float*)carve((size_t)N_GRAPHS * 256 * 4);
    int* deg = (int*)carve((size_t)N_NODES * 4);
    int* cnt = (int*)carve((size_t)N_NODES * 4);
    int* incl = (int*)carve((size_t)N_NODES * 4);
    int* offs = (int*)carve((size_t)(N_NODES + 1) * 4);
    int* bsums = (int*)carve(64 * 4);
    int* csr = (int*)carve((size_t)EP * 4);
    int* goffs = (int*)carve((size_t)(N_GRAPHS + 1) * 4);
    const bool mfma_ok = (off <= ws_size);
    float* Afp = (float*)Ah;  // fallback fp32 buffer aliases Ah+Al
    float* C = (float*)Ah;    // layer-2 fp32 scratch reuses Ah region
    // layer-0 h-space buffers inside B region:
    float* h0 = B;
    unsigned short* hth = (unsigned short*)((char*)B + (size_t)N_NODES * 64 * 4);
    unsigned short* htl = (unsigned short*)((char*)hth + (size_t)N_PAD * 256 * 2);

    const int TPB = 256;
    int gbN = (N_NODES + TPB - 1) / TPB;
    int gbE = (EP + TPB - 1) / TPB;
    int nbScan = (N_NODES + 1023) / 1024;

    hipMemsetAsync(deg, 0, (size_t)N_NODES * 4, stream);
    hipMemsetAsync(cnt, 0, (size_t)N_NODES * 4, stream);
    k_deg<<<gbE, TPB, 0, stream>>>(ei, deg);
    k_scanA<<<nbScan, 1024, 0, stream>>>(deg, incl, bsums);
    k_scanB<<<1, 64, 0, stream>>>(bsums, nbScan);
    k_scanC<<<gbN, TPB, 0, stream>>>(incl, deg, bsums, offs);
    k_scatter<<<gbE, TPB, 0, stream>>>(ei, offs, cnt, csr);
    k_graph_bounds<<<gbN, TPB, 0, stream>>>(batch, goffs);

    int gbNode4 = (N_NODES + 3) / 4;
    dim3 g512(4, 392);  // swizzled: 392 = ceil(391/8)*8
    dim3 g128(1, 391);

    if (mfma_ok) {
        // ---- layer 0 (h-space aggregation; x0 = (sum_e a_e h[src]) @ W0^T + b0) ----
        k_node_init<<<(N_NODES * EMB + TPB - 1) / TPB, TPB, 0, stream>>>(x, depth, emb_table, depth_w, depth_b, h0);
        k_wproj<<<1, TPB, 0, stream>>>(W0, as0, ad0, wtil);
        k_split<<<(512 * 64 / 4 + TPB - 1) / TPB, TPB, 0, stream>>>(W0, Wh, Wl, nullptr, 512 * 64 / 4, 512 * 64);
        k_al0<<<gbNode4, TPB, 0, stream>>>(h0, wtil, als, ald, bn);
        k_agg0<<<NB_AGG, TPB, 0, stream>>>(h0, als, ald, offs, csr, hth, htl);
        k_gemm0h<<<g512, TPB, 0, stream>>>(hth, htl, Wh, Wl, b0, Ah, Al, bn);
        k_bnsplit<<<(N_NODES * 512 / 4 + TPB - 1) / TPB, TPB, 0, stream>>>(Ah, Al, bn, g0, be0, 512, N_NODES * 512 / 4);
        // ---- layer 1: [N,512] -> [N,512] ----
        k_split<<<(512 * 512 / 4 + TPB - 1) / TPB, TPB, 0, stream>>>(W1, Wh, Wl, bn, 512 * 512 / 4, 512 * 512);
        k_gemm_mfma<<<g512, TPB, 0, stream>>>(Ah, Al, Wh, Wl, as1, ad1, als, ald, B, 512, 512, HEADS);
        k_aggregate<512, HEADS, true><<<NB_AGG, TPB, 0, stream>>>(B, als, ald, offs, csr, b1, nullptr, Ah, Al, bn);
        k_bnsplit<<<(N_NODES * 512 / 4 + TPB - 1) / TPB, TPB, 0, stream>>>(Ah, Al, bn, g1, be1, 512, N_NODES * 512 / 4);
        // ---- layer 2: [N,512] -> [N,128] ----
        k_split<<<(128 * 512 / 4 + TPB - 1) / TPB, TPB, 0, stream>>>(W2, Wh, Wl, bn, 128 * 512 / 4, 128 * 512);
        k_gemm_mfma<<<g128, TPB, 0, stream>>>(Ah, Al, Wh, Wl, as2, ad2, als, ald, B, 512, 128, 1);
    } else {
        k_node_init<<<(N_NODES * EMB + TPB - 1) / TPB, TPB, 0, stream>>>(x, depth, emb_table, depth_w, depth_b, Afp);
        int gbRows = N_PAD / 128;
        k_gemm<<<dim3(4, gbRows), TPB, 0, stream>>>(Afp, W0, B, N_NODES, 64, 512);
        k_al<<<gbNode4, TPB, 0, stream>>>(B, as0, ad0, als, ald, bn, 512, HEADS);
        k_aggregate<512, HEADS, false><<<NB_AGG, TPB, 0, stream>>>(B, als, ald, offs, csr, b0, Afp, nullptr, nullptr, bn);
        k_bn_apply<<<(N_NODES * 512 / 4 + TPB - 1) / TPB, TPB, 0, stream>>>(Afp, bn, g0, be0, 512, N_NODES * 512 / 4);
        k_gemm<<<dim3(4, gbRows), TPB, 0, stream>>>(Afp, W1, B, N_NODES, 512, 512);
        k_al<<<gbNode4, TPB, 0, stream>>>(B, as1, ad1, als, ald, bn, 512, HEADS);
        k_aggregate<512, HEADS, false><<<NB_AGG, TPB, 0, stream>>>(B, als, ald, offs, csr, b1, Afp, nullptr, nullptr, bn);
        k_bn_apply<<<(N_NODES * 512 / 4 + TPB - 1) / TPB, TPB, 0, stream>>>(Afp, bn, g1, be1, 512, N_NODES * 512 / 4);
        k_gemm<<<dim3(1, gbRows), TPB, 0, stream>>>(Afp, W2, B, N_NODES, 512, 128);
        k_al<<<gbNode4, TPB, 0, stream>>>(B, as2, ad2, als, ald, bn, 128, 1);
    }

    // ---- layer 2 tail (shared; bn zeroed by k_split W2 on mfma path, k_al on fallback) ----
    k_aggregate<128, 1, false><<<NB_AGG, TPB, 0, stream>>>(B, als, ald, offs, csr, b2, C, nullptr, nullptr, bn);
    k_bn_apply<<<(N_NODES * 128 / 4 + TPB - 1) / TPB, TPB, 0, stream>>>(C, bn, g2, be2, 128, N_NODES * 128 / 4);

    k_pool<<<N_GRAPHS, 128, 0, stream>>>(C, goffs, emb);
    k_classify<<<N_GRAPHS, TPB, 0, stream>>>(emb, cw1, cb1, cw2, cb2, out);
}